// Round 1
// baseline (916.119 us; speedup 1.0000x reference)
//
#include <hip/hip_runtime.h>
#include <math.h>

#define D 128
#define GCN_NUM 3
#define HEADS 8
#define HD 16
#define L_SEQ 100
#define LEAKY 0.01f

// ---------------- graph build ----------------

__global__ void fill_deg(int* __restrict__ deg, int n) {
  int i = blockIdx.x * blockDim.x + threadIdx.x;
  if (i < n) deg[i] = 1;  // self-loop
}

__global__ void count_deg(const int* __restrict__ e0, const int* __restrict__ e1,
                          int* __restrict__ deg, int E) {
  int stride = gridDim.x * blockDim.x;
  for (int i = blockIdx.x * blockDim.x + threadIdx.x; i < E; i += stride) {
    atomicAdd(&deg[e0[i]], 1);
    atomicAdd(&deg[e1[i]], 1);
  }
}

__global__ void compute_dis(const int* __restrict__ deg, float* __restrict__ dis, int n) {
  int i = blockIdx.x * blockDim.x + threadIdx.x;
  if (i < n) dis[i] = 1.0f / sqrtf((float)deg[i]);  // deg >= 1 always (self-loop)
}

// single-block exclusive scan over n ints (n ~ 50000; trivial runtime)
__global__ void scan_kernel(const int* __restrict__ deg, int* __restrict__ row_ptr,
                            int* __restrict__ cursor, int n) {
  __shared__ int buf[2][1024];
  __shared__ int carry_s;
  int tid = threadIdx.x;
  if (tid == 0) carry_s = 0;
  __syncthreads();
  for (int base = 0; base < n; base += 1024) {
    int i = base + tid;
    int v = (i < n) ? deg[i] : 0;
    int cur = 0;
    buf[0][tid] = v;
    __syncthreads();
    for (int off = 1; off < 1024; off <<= 1) {
      int t = buf[cur][tid];
      if (tid >= off) t += buf[cur][tid - off];
      buf[cur ^ 1][tid] = t;
      cur ^= 1;
      __syncthreads();
    }
    int incl = buf[cur][tid];
    int excl = incl - v;
    int carry = carry_s;
    if (i < n) { int pval = carry + excl; row_ptr[i] = pval; cursor[i] = pval; }
    __syncthreads();  // all reads of carry_s done
    if (tid == 1023) carry_s = carry + buf[cur][1023];
    __syncthreads();
  }
  if (tid == 0) row_ptr[n] = carry_s;
}

__global__ void scatter_edges(const int* __restrict__ e0, const int* __restrict__ e1,
                              const float* __restrict__ dv, const float* __restrict__ dis,
                              int* __restrict__ cursor, int* __restrict__ ccol,
                              float* __restrict__ cw, int E, int N) {
  int total = 2 * E + N;
  int stride = gridDim.x * blockDim.x;
  for (int i = blockIdx.x * blockDim.x + threadIdx.x; i < total; i += stride) {
    int r, c; float d;
    if (i < E)            { r = e0[i];     c = e1[i];     d = dv[i]; }
    else if (i < 2 * E)   { r = e1[i - E]; c = e0[i - E]; d = dv[i - E]; }
    else                  { r = i - 2 * E; c = r;         d = 0.f; }
    float w = expf(-d * d) * dis[r] * dis[c];
    int pos = atomicAdd(&cursor[r], 1);
    ccol[pos] = c;
    cw[pos] = w;
  }
}

// ---------------- GCN ----------------

// one row per block; thread d owns feature d; register accumulation (no atomics)
__global__ __launch_bounds__(128) void spmm_kernel(
    const int* __restrict__ row_ptr, const int* __restrict__ ccol,
    const float* __restrict__ cw, const float* __restrict__ enc_in,
    float* __restrict__ agg, int n) {
  int r = blockIdx.x;
  if (r >= n) return;
  int d = threadIdx.x;
  int s = row_ptr[r], e = row_ptr[r + 1];
  float acc = 0.f;
  for (int i = s; i < e; ++i)
    acc += cw[i] * enc_in[(size_t)ccol[i] * D + d];
  agg[(size_t)r * D + d] = acc;
}

// fused: enc = normalize(leaky_relu(agg @ W^T + b)); 16 rows per 128-thread block
__global__ __launch_bounds__(128) void dense_layer(
    const float* __restrict__ agg, const float* __restrict__ W,
    const float* __restrict__ bias, float* __restrict__ enc, int n) {
  const int ROWS = 16;
  __shared__ float a_s[ROWS][D];
  __shared__ float w_s[D][33];  // k-chunk of W, padded (+1) for conflict-free
  __shared__ float pw[2];
  int tid = threadIdx.x;
  int r0 = blockIdx.x * ROWS;
#pragma unroll
  for (int r = 0; r < ROWS; ++r) {
    int row = r0 + r;
    a_s[r][tid] = (row < n) ? agg[(size_t)row * D + tid] : 0.f;
  }
  float acc[ROWS];
#pragma unroll
  for (int r = 0; r < ROWS; ++r) acc[r] = 0.f;
  for (int kc = 0; kc < D; kc += 32) {
    __syncthreads();
    const float4* w4 = reinterpret_cast<const float4*>(W + (size_t)tid * D + kc);
#pragma unroll
    for (int k4 = 0; k4 < 8; ++k4) {
      float4 w = w4[k4];
      w_s[tid][k4 * 4 + 0] = w.x; w_s[tid][k4 * 4 + 1] = w.y;
      w_s[tid][k4 * 4 + 2] = w.z; w_s[tid][k4 * 4 + 3] = w.w;
    }
    __syncthreads();
#pragma unroll
    for (int r = 0; r < ROWS; ++r) {
      float s = 0.f;
#pragma unroll
      for (int k = 0; k < 32; ++k) s += a_s[r][kc + k] * w_s[tid][k];
      acc[r] += s;
    }
  }
  float bj = bias[tid];
  for (int r = 0; r < ROWS; ++r) {
    int row = r0 + r;
    float t = acc[r] + bj;
    t = (t > 0.f) ? t : LEAKY * t;
    float ss = t * t;
#pragma unroll
    for (int off = 1; off < 64; off <<= 1) ss += __shfl_xor(ss, off);
    if ((tid & 63) == 0) pw[tid >> 6] = ss;
    __syncthreads();
    float tot = pw[0] + pw[1];
    float scale = 1.0f / fmaxf(sqrtf(tot), 1e-12f);
    if (row < n) enc[(size_t)row * D + tid] = t * scale;
    __syncthreads();
  }
}

// ---------------- gather + attention ----------------

__global__ void gather_rows(const float* __restrict__ src, const int* __restrict__ idx,
                            float* __restrict__ dst, int M) {
  int i = blockIdx.x;
  if (i < M) dst[(size_t)i * D + threadIdx.x] = src[(size_t)idx[i] * D + threadIdx.x];
}

// qkv[i][j] = dot(geo[i], in_w[j]) + in_b[j]; 16 rows / block, 384 threads (one per j)
__global__ __launch_bounds__(384) void qkv_kernel(
    const float* __restrict__ x, const float* __restrict__ Wi,
    const float* __restrict__ bi, float* __restrict__ qkv, int M) {
  const int ROWS = 16;
  __shared__ float a_s[ROWS][D];
  int tid = threadIdx.x;
  int r0 = blockIdx.x * ROWS;
  for (int idx = tid; idx < ROWS * D; idx += 384) {
    int r = idx >> 7, c = idx & 127;
    int row = r0 + r;
    a_s[r][c] = (row < M) ? x[(size_t)row * D + c] : 0.f;
  }
  __syncthreads();
  float acc[ROWS];
#pragma unroll
  for (int r = 0; r < ROWS; ++r) acc[r] = 0.f;
  const float4* w4 = reinterpret_cast<const float4*>(Wi + (size_t)tid * D);
  for (int k4 = 0; k4 < D / 4; ++k4) {
    float4 w = w4[k4];
    int k = k4 * 4;
#pragma unroll
    for (int r = 0; r < ROWS; ++r)
      acc[r] += a_s[r][k] * w.x + a_s[r][k + 1] * w.y + a_s[r][k + 2] * w.z + a_s[r][k + 3] * w.w;
  }
  float bj = bi[tid];
  for (int r = 0; r < ROWS; ++r) {
    int row = r0 + r;
    if (row < M) qkv[(size_t)row * 384 + tid] = acc[r] + bj;
  }
}

// one block per (b, h): scores->softmax->PV entirely on-chip
__global__ __launch_bounds__(128) void attn_kernel(
    const float* __restrict__ qkv, float* __restrict__ o) {
  __shared__ float k_s[L_SEQ][HD];
  __shared__ float v_s[L_SEQ][HD];
  __shared__ float sc[L_SEQ][L_SEQ + 1];
  int b = blockIdx.x / HEADS;
  int h = blockIdx.x % HEADS;
  int tid = threadIdx.x;
  const size_t rowbase = (size_t)b * L_SEQ;
  for (int idx = tid; idx < L_SEQ * HD; idx += 128) {
    int l = idx >> 4, d2 = idx & 15;
    const float* base = qkv + (rowbase + l) * 384 + h * HD + d2;
    k_s[l][d2] = base[128];
    v_s[l][d2] = base[256];
  }
  __syncthreads();
  if (tid < L_SEQ) {
    float q[HD];
    const float* qp = qkv + (rowbase + tid) * 384 + h * HD;
#pragma unroll
    for (int d2 = 0; d2 < HD; ++d2) q[d2] = qp[d2];
    float m = -1e30f;
    for (int j = 0; j < L_SEQ; ++j) {
      float s = 0.f;
#pragma unroll
      for (int d2 = 0; d2 < HD; ++d2) s += q[d2] * k_s[j][d2];
      s *= 0.25f;  // 1/sqrt(16)
      sc[tid][j] = s;
      m = fmaxf(m, s);
    }
    float sum = 0.f;
    for (int j = 0; j < L_SEQ; ++j) {
      float e = expf(sc[tid][j] - m);
      sc[tid][j] = e;
      sum += e;
    }
    float inv = 1.f / sum;
    float oacc[HD];
#pragma unroll
    for (int d2 = 0; d2 < HD; ++d2) oacc[d2] = 0.f;
    for (int j = 0; j < L_SEQ; ++j) {
      float p = sc[tid][j];
#pragma unroll
      for (int d2 = 0; d2 < HD; ++d2) oacc[d2] += p * v_s[j][d2];
    }
    float* op = o + (rowbase + tid) * D + h * HD;
#pragma unroll
    for (int d2 = 0; d2 < HD; ++d2) op[d2] = oacc[d2] * inv;
  }
}

// aggr[b] = mean_l(o[b][l]) @ out_w^T + out_b   (mean commutes with linear)
__global__ __launch_bounds__(128) void out_mean_kernel(
    const float* __restrict__ o, const float* __restrict__ Wo,
    const float* __restrict__ bo, float* __restrict__ out, int L) {
  __shared__ float m_s[D];
  int b = blockIdx.x, tid = threadIdx.x;
  float s = 0.f;
  for (int l = 0; l < L; ++l) s += o[((size_t)b * L + l) * D + tid];
  m_s[tid] = s / (float)L;
  __syncthreads();
  const float4* w4 = reinterpret_cast<const float4*>(Wo + (size_t)tid * D);
  float acc = 0.f;
  for (int k4 = 0; k4 < D / 4; ++k4) {
    float4 w = w4[k4];
    int k = k4 * 4;
    acc += m_s[k] * w.x + m_s[k + 1] * w.y + m_s[k + 2] * w.z + m_s[k + 3] * w.w;
  }
  out[(size_t)b * D + tid] = acc + bo[tid];
}

// ---------------- launch ----------------

extern "C" void kernel_launch(void* const* d_in, const int* in_sizes, int n_in,
                              void* d_out, int out_size, void* d_ws, size_t ws_size,
                              hipStream_t stream) {
  const float* embeds   = (const float*)d_in[0];
  const float* gcn_W    = (const float*)d_in[1];
  const float* gcn_b    = (const float*)d_in[2];
  const float* in_w     = (const float*)d_in[3];
  const float* in_b     = (const float*)d_in[4];
  const float* out_w    = (const float*)d_in[5];
  const float* out_b    = (const float*)d_in[6];
  const float* dist_vec = (const float*)d_in[7];
  const int*   edges    = (const int*)d_in[8];
  const int*   x_idx    = (const int*)d_in[9];
  const int*   poi_idx  = (const int*)d_in[10];
  float* out = (float*)d_out;

  int N  = in_sizes[0] / D;   // 50000
  int E  = in_sizes[7];       // 400000
  int BL = in_sizes[9];       // 6400
  int B  = in_sizes[10];      // 64
  int L  = BL / B;            // 100
  const int* e0 = edges;
  const int* e1 = edges + E;
  size_t total_edges = (size_t)2 * E + N;  // 850000

  char* p = (char*)d_ws;
  auto alloc = [&](size_t bytes) { char* q = p; p += (bytes + 255) & ~(size_t)255; return q; };
  int*   deg     = (int*)alloc((size_t)N * 4);
  int*   row_ptr = (int*)alloc((size_t)(N + 1) * 4);
  int*   cursor  = (int*)alloc((size_t)N * 4);
  float* dis     = (float*)alloc((size_t)N * 4);
  int*   ccol    = (int*)alloc(total_edges * 4);
  float* cw      = (float*)alloc(total_edges * 4);
  float* agg     = (float*)alloc((size_t)N * D * 4);
  float* enc     = (float*)alloc((size_t)N * D * 4);
  float* geo     = (float*)alloc((size_t)BL * D * 4);
  float* qkv     = (float*)alloc((size_t)BL * 384 * 4);
  float* obuf    = (float*)alloc((size_t)BL * D * 4);

  fill_deg<<<(N + 255) / 256, 256, 0, stream>>>(deg, N);
  count_deg<<<1024, 256, 0, stream>>>(e0, e1, deg, E);
  compute_dis<<<(N + 255) / 256, 256, 0, stream>>>(deg, dis, N);
  scan_kernel<<<1, 1024, 0, stream>>>(deg, row_ptr, cursor, N);
  scatter_edges<<<2048, 256, 0, stream>>>(e0, e1, dist_vec, dis, cursor, ccol, cw, E, N);

  const float* cur_in = embeds;
  for (int i = 0; i < GCN_NUM; ++i) {
    spmm_kernel<<<N, 128, 0, stream>>>(row_ptr, ccol, cw, cur_in, agg, N);
    dense_layer<<<(N + 15) / 16, 128, 0, stream>>>(
        agg, gcn_W + (size_t)i * D * D, gcn_b + (size_t)i * D, enc, N);
    cur_in = enc;
  }

  gather_rows<<<BL, 128, 0, stream>>>(enc, x_idx, geo, BL);
  gather_rows<<<B, 128, 0, stream>>>(enc, poi_idx, out + (size_t)B * D, B);
  qkv_kernel<<<(BL + 15) / 16, 384, 0, stream>>>(geo, in_w, in_b, qkv, BL);
  attn_kernel<<<B * HEADS, 128, 0, stream>>>(qkv, obuf);
  out_mean_kernel<<<B, 128, 0, stream>>>(obuf, out_w, out_b, out, L);
}

// Round 4
// 517.930 us; speedup vs baseline: 1.7688x; 1.7688x over previous
//
#include <hip/hip_runtime.h>
#include <math.h>

#define D 128
#define GCN_NUM 3
#define HEADS 8
#define HD 16
#define L_SEQ 100
#define LEAKY 0.01f

typedef __attribute__((ext_vector_type(8))) short short8v;
typedef __attribute__((ext_vector_type(4))) float f32x4;

__device__ __forceinline__ unsigned f2bf(float x) {
  unsigned u = __float_as_uint(x);
  return (u + 0x7FFFu + ((u >> 16) & 1u)) >> 16;
}
__device__ __forceinline__ float bflo2f(unsigned u) {  // low ushort -> float
  return __uint_as_float(u << 16);
}
__device__ __forceinline__ float bfhi2f(unsigned u) {  // high ushort -> float
  return __uint_as_float(u & 0xFFFF0000u);
}

// ---------------- dtype convert ----------------

__global__ void f32_to_bf16_kernel(const float* __restrict__ src,
                                   unsigned short* __restrict__ dst, int n4) {
  int i = blockIdx.x * blockDim.x + threadIdx.x;
  if (i < n4) {
    float4 v = reinterpret_cast<const float4*>(src)[i];
    uint2 o;
    o.x = f2bf(v.x) | (f2bf(v.y) << 16);
    o.y = f2bf(v.z) | (f2bf(v.w) << 16);
    reinterpret_cast<uint2*>(dst)[i] = o;
  }
}

// ---------------- graph build ----------------

__global__ void fill_deg(int* __restrict__ deg, int n) {
  int i = blockIdx.x * blockDim.x + threadIdx.x;
  if (i < n) deg[i] = 1;  // self-loop
}

__global__ void count_deg(const int* __restrict__ e0, const int* __restrict__ e1,
                          int* __restrict__ deg, int E) {
  int stride = gridDim.x * blockDim.x;
  for (int i = blockIdx.x * blockDim.x + threadIdx.x; i < E; i += stride) {
    atomicAdd(&deg[e0[i]], 1);
    atomicAdd(&deg[e1[i]], 1);
  }
}

__global__ void compute_dis(const int* __restrict__ deg, float* __restrict__ dis, int n) {
  int i = blockIdx.x * blockDim.x + threadIdx.x;
  if (i < n) dis[i] = 1.0f / sqrtf((float)deg[i]);  // deg >= 1 always
}

// single-block exclusive scan, shuffle-based (2 barriers per 1024-chunk)
__global__ void scan_kernel(const int* __restrict__ deg, int* __restrict__ row_ptr,
                            int* __restrict__ cursor, int n) {
  __shared__ int wsum[16];
  __shared__ int carry_s;
  int tid = threadIdx.x, lane = tid & 63, wid = tid >> 6;
  if (tid == 0) carry_s = 0;
  __syncthreads();
  for (int base = 0; base < n; base += 1024) {
    int i = base + tid;
    int v = (i < n) ? deg[i] : 0;
    int x = v;
#pragma unroll
    for (int off = 1; off < 64; off <<= 1) {
      int y = __shfl_up(x, off);
      if (lane >= off) x += y;
    }
    if (lane == 63) wsum[wid] = x;
    __syncthreads();
    if (wid == 0) {
      int s = (lane < 16) ? wsum[lane] : 0;
#pragma unroll
      for (int off = 1; off < 16; off <<= 1) {
        int y = __shfl_up(s, off);
        if (lane >= off) s += y;
      }
      if (lane < 16) wsum[lane] = s;  // inclusive over waves
    }
    __syncthreads();
    int woff = (wid == 0) ? 0 : wsum[wid - 1];
    int carry = carry_s;
    if (i < n) {
      int pval = carry + woff + (x - v);
      row_ptr[i] = pval;
      cursor[i] = pval;
    }
    __syncthreads();
    if (tid == 1023) carry_s = carry + wsum[15];
    __syncthreads();
  }
  if (tid == 0) row_ptr[n] = carry_s;
}

__global__ void scatter_edges(const int* __restrict__ e0, const int* __restrict__ e1,
                              const float* __restrict__ dv, const float* __restrict__ dis,
                              int* __restrict__ cursor, int* __restrict__ ccol,
                              float* __restrict__ cw, int E, int N) {
  int total = 2 * E + N;
  int stride = gridDim.x * blockDim.x;
  for (int i = blockIdx.x * blockDim.x + threadIdx.x; i < total; i += stride) {
    int r, c; float d;
    if (i < E)          { r = e0[i];     c = e1[i];     d = dv[i]; }
    else if (i < 2 * E) { r = e1[i - E]; c = e0[i - E]; d = dv[i - E]; }
    else                { r = i - 2 * E; c = r;         d = 0.f; }
    float w = expf(-d * d) * dis[r] * dis[c];
    int pos = atomicAdd(&cursor[r], 1);
    ccol[pos] = c;
    cw[pos] = w;
  }
}

// ---------------- GCN ----------------

// wave-per-row SpMM over bf16 rows; lane handles features 2l, 2l+1; f32 accumulate
__global__ __launch_bounds__(256) void spmm_bf(
    const int* __restrict__ row_ptr, const int* __restrict__ ccol,
    const float* __restrict__ cw, const unsigned short* __restrict__ enc,
    unsigned short* __restrict__ agg, int n) {
  int r = blockIdx.x * 4 + (threadIdx.x >> 6);
  if (r >= n) return;
  int l = threadIdx.x & 63;
  int s = row_ptr[r], e = row_ptr[r + 1];
  float a0 = 0.f, a1 = 0.f;
  int c = 0; float wv = 0.f;
  if (s < e) { c = ccol[s]; wv = cw[s]; }
  for (int i = s; i < e; ++i) {
    int cc = c; float wc = wv;
    if (i + 1 < e) { c = ccol[i + 1]; wv = cw[i + 1]; }
    unsigned u = *reinterpret_cast<const unsigned*>(enc + (size_t)cc * D + 2 * l);
    a0 = fmaf(wc, bflo2f(u), a0);
    a1 = fmaf(wc, bfhi2f(u), a1);
  }
  unsigned o = f2bf(a0) | (f2bf(a1) << 16);
  *reinterpret_cast<unsigned*>(agg + (size_t)r * D + 2 * l) = o;
}

// enc = normalize(leaky_relu(A @ W^T + b)) via MFMA bf16.
// 256 threads = 4 waves; block covers 128 rows (2 row-tiles of 16 per wave).
__global__ __launch_bounds__(256) void dense_mfma(
    const unsigned short* __restrict__ A,    // [Npad][128] bf16
    const unsigned short* __restrict__ Wb,   // [128 out][128 in] bf16
    const float* __restrict__ bias,
    unsigned short* __restrict__ enc,        // [Npad][128] bf16
    int n) {
  __shared__ unsigned short Wl[128 * 136];   // padded stride: 272 B (17x16B)
  int tid = threadIdx.x;
  {
    int cg = (tid & 15) * 8;
    int r0 = tid >> 4;
#pragma unroll
    for (int i = 0; i < 8; ++i) {
      int row = r0 + i * 16;
      *reinterpret_cast<short8v*>(&Wl[row * 136 + cg]) =
          *reinterpret_cast<const short8v*>(Wb + row * D + cg);
    }
  }
  __syncthreads();
  int w = tid >> 6, lane = tid & 63;
  int lr = lane & 15, lg = lane >> 4;
#pragma unroll
  for (int rt = 0; rt < 2; ++rt) {
    int rbase = blockIdx.x * 128 + rt * 64 + w * 16;
    f32x4 acc[8];
#pragma unroll
    for (int j = 0; j < 8; ++j) acc[j] = f32x4{0.f, 0.f, 0.f, 0.f};
    const unsigned short* arow = A + (size_t)(rbase + lr) * D + lg * 8;
#pragma unroll
    for (int ks = 0; ks < 4; ++ks) {
      short8v a = *reinterpret_cast<const short8v*>(arow + ks * 32);
#pragma unroll
      for (int jt = 0; jt < 8; ++jt) {
        short8v b = *reinterpret_cast<const short8v*>(&Wl[(jt * 16 + lr) * 136 + ks * 32 + lg * 8]);
        acc[jt] = __builtin_amdgcn_mfma_f32_16x16x32_bf16(a, b, acc[jt], 0, 0, 0);
      }
    }
    float vals[8][4];
    float ss[4] = {0.f, 0.f, 0.f, 0.f};
#pragma unroll
    for (int jt = 0; jt < 8; ++jt) {
      float bj = bias[jt * 16 + lr];
#pragma unroll
      for (int i = 0; i < 4; ++i) {
        float t = acc[jt][i] + bj;
        t = (t > 0.f) ? t : LEAKY * t;
        vals[jt][i] = t;
        ss[i] += t * t;
      }
    }
#pragma unroll
    for (int i = 0; i < 4; ++i) {
      float s = ss[i];
      s += __shfl_xor(s, 1); s += __shfl_xor(s, 2);
      s += __shfl_xor(s, 4); s += __shfl_xor(s, 8);
      ss[i] = 1.0f / fmaxf(sqrtf(s), 1e-12f);
    }
#pragma unroll
    for (int i = 0; i < 4; ++i) {
      int row = rbase + lg * 4 + i;
      if (row < n) {
#pragma unroll
        for (int jt = 0; jt < 8; ++jt)
          enc[(size_t)row * D + jt * 16 + lr] = (unsigned short)f2bf(vals[jt][i] * ss[i]);
      }
    }
  }
}

// ---------------- gather + attention ----------------

__global__ void gather_bf_to_f32(const unsigned short* __restrict__ src,
                                 const int* __restrict__ idx,
                                 float* __restrict__ dst, int M) {
  int i = blockIdx.x;
  if (i < M) {
    int t = threadIdx.x;
    dst[(size_t)i * D + t] = bflo2f(src[(size_t)idx[i] * D + t]);
  }
}

__global__ __launch_bounds__(384) void qkv_kernel(
    const float* __restrict__ x, const float* __restrict__ Wi,
    const float* __restrict__ bi, float* __restrict__ qkv, int M) {
  const int ROWS = 16;
  __shared__ float a_s[ROWS][D];
  int tid = threadIdx.x;
  int r0 = blockIdx.x * ROWS;
  for (int idx = tid; idx < ROWS * D; idx += 384) {
    int r = idx >> 7, c = idx & 127;
    int row = r0 + r;
    a_s[r][c] = (row < M) ? x[(size_t)row * D + c] : 0.f;
  }
  __syncthreads();
  float acc[ROWS];
#pragma unroll
  for (int r = 0; r < ROWS; ++r) acc[r] = 0.f;
  const float4* w4 = reinterpret_cast<const float4*>(Wi + (size_t)tid * D);
  for (int k4 = 0; k4 < D / 4; ++k4) {
    float4 w = w4[k4];
    int k = k4 * 4;
#pragma unroll
    for (int r = 0; r < ROWS; ++r)
      acc[r] += a_s[r][k] * w.x + a_s[r][k + 1] * w.y + a_s[r][k + 2] * w.z + a_s[r][k + 3] * w.w;
  }
  float bj = bi[tid];
  for (int r = 0; r < ROWS; ++r) {
    int row = r0 + r;
    if (row < M) qkv[(size_t)row * 384 + tid] = acc[r] + bj;
  }
}

__global__ __launch_bounds__(128) void attn_kernel(
    const float* __restrict__ qkv, float* __restrict__ o) {
  __shared__ float k_s[L_SEQ][HD];
  __shared__ float v_s[L_SEQ][HD];
  __shared__ float sc[L_SEQ][L_SEQ + 1];
  int b = blockIdx.x / HEADS;
  int h = blockIdx.x % HEADS;
  int tid = threadIdx.x;
  const size_t rowbase = (size_t)b * L_SEQ;
  for (int idx = tid; idx < L_SEQ * HD; idx += 128) {
    int l = idx >> 4, d2 = idx & 15;
    const float* base = qkv + (rowbase + l) * 384 + h * HD + d2;
    k_s[l][d2] = base[128];
    v_s[l][d2] = base[256];
  }
  __syncthreads();
  if (tid < L_SEQ) {
    float q[HD];
    const float* qp = qkv + (rowbase + tid) * 384 + h * HD;
#pragma unroll
    for (int d2 = 0; d2 < HD; ++d2) q[d2] = qp[d2];
    float m = -1e30f;
    for (int j = 0; j < L_SEQ; ++j) {
      float s = 0.f;
#pragma unroll
      for (int d2 = 0; d2 < HD; ++d2) s += q[d2] * k_s[j][d2];
      s *= 0.25f;
      sc[tid][j] = s;
      m = fmaxf(m, s);
    }
    float sum = 0.f;
    for (int j = 0; j < L_SEQ; ++j) {
      float e = expf(sc[tid][j] - m);
      sc[tid][j] = e;
      sum += e;
    }
    float inv = 1.f / sum;
    float oacc[HD];
#pragma unroll
    for (int d2 = 0; d2 < HD; ++d2) oacc[d2] = 0.f;
    for (int j = 0; j < L_SEQ; ++j) {
      float p = sc[tid][j];
#pragma unroll
      for (int d2 = 0; d2 < HD; ++d2) oacc[d2] += p * v_s[j][d2];
    }
    float* op = o + (rowbase + tid) * D + h * HD;
#pragma unroll
    for (int d2 = 0; d2 < HD; ++d2) op[d2] = oacc[d2] * inv;
  }
}

__global__ __launch_bounds__(128) void out_mean_kernel(
    const float* __restrict__ o, const float* __restrict__ Wo,
    const float* __restrict__ bo, float* __restrict__ out, int L) {
  __shared__ float m_s[D];
  int b = blockIdx.x, tid = threadIdx.x;
  float s = 0.f;
  for (int l = 0; l < L; ++l) s += o[((size_t)b * L + l) * D + tid];
  m_s[tid] = s / (float)L;
  __syncthreads();
  const float4* w4 = reinterpret_cast<const float4*>(Wo + (size_t)tid * D);
  float acc = 0.f;
  for (int k4 = 0; k4 < D / 4; ++k4) {
    float4 w = w4[k4];
    int k = k4 * 4;
    acc += m_s[k] * w.x + m_s[k + 1] * w.y + m_s[k + 2] * w.z + m_s[k + 3] * w.w;
  }
  out[(size_t)b * D + tid] = acc + bo[tid];
}

// ---------------- launch ----------------

extern "C" void kernel_launch(void* const* d_in, const int* in_sizes, int n_in,
                              void* d_out, int out_size, void* d_ws, size_t ws_size,
                              hipStream_t stream) {
  const float* embeds   = (const float*)d_in[0];
  const float* gcn_W    = (const float*)d_in[1];
  const float* gcn_b    = (const float*)d_in[2];
  const float* in_w     = (const float*)d_in[3];
  const float* in_b     = (const float*)d_in[4];
  const float* out_w    = (const float*)d_in[5];
  const float* out_b    = (const float*)d_in[6];
  const float* dist_vec = (const float*)d_in[7];
  const int*   edges    = (const int*)d_in[8];
  const int*   x_idx    = (const int*)d_in[9];
  const int*   poi_idx  = (const int*)d_in[10];
  float* out = (float*)d_out;

  int N  = in_sizes[0] / D;   // 50000
  int E  = in_sizes[7];       // 400000
  int BL = in_sizes[9];       // 6400
  int B  = in_sizes[10];      // 64
  int L  = BL / B;            // 100
  const int* e0 = edges;
  const int* e1 = edges + E;
  size_t total_edges = (size_t)2 * E + N;          // 850000
  int Npad = ((N + 127) / 128) * 128;              // 50048

  char* p = (char*)d_ws;
  auto alloc = [&](size_t bytes) { char* q = p; p += (bytes + 255) & ~(size_t)255; return q; };
  int*   deg     = (int*)alloc((size_t)N * 4);
  int*   row_ptr = (int*)alloc((size_t)(N + 1) * 4);
  int*   cursor  = (int*)alloc((size_t)N * 4);
  float* dis     = (float*)alloc((size_t)N * 4);
  int*   ccol    = (int*)alloc(total_edges * 4);
  float* cw      = (float*)alloc(total_edges * 4);
  unsigned short* emb_bf = (unsigned short*)alloc((size_t)Npad * D * 2);
  unsigned short* W_bf   = (unsigned short*)alloc((size_t)GCN_NUM * D * D * 2);
  unsigned short* agg_bf = (unsigned short*)alloc((size_t)Npad * D * 2);
  unsigned short* enc_bf = (unsigned short*)alloc((size_t)Npad * D * 2);
  float* geo  = (float*)alloc((size_t)BL * D * 4);
  float* qkv  = (float*)alloc((size_t)BL * 384 * 4);
  float* obuf = (float*)alloc((size_t)BL * D * 4);

  // convert inputs to bf16
  int n4e = N * D / 4;
  f32_to_bf16_kernel<<<(n4e + 255) / 256, 256, 0, stream>>>(embeds, emb_bf, n4e);
  int n4w = GCN_NUM * D * D / 4;
  f32_to_bf16_kernel<<<(n4w + 255) / 256, 256, 0, stream>>>(gcn_W, W_bf, n4w);

  // graph build
  fill_deg<<<(N + 255) / 256, 256, 0, stream>>>(deg, N);
  count_deg<<<1024, 256, 0, stream>>>(e0, e1, deg, E);
  compute_dis<<<(N + 255) / 256, 256, 0, stream>>>(deg, dis, N);
  scan_kernel<<<1, 1024, 0, stream>>>(deg, row_ptr, cursor, N);
  scatter_edges<<<2048, 256, 0, stream>>>(e0, e1, dist_vec, dis, cursor, ccol, cw, E, N);

  // GCN layers (bf16 storage, MFMA dense)
  const unsigned short* cur_in = emb_bf;
  for (int i = 0; i < GCN_NUM; ++i) {
    spmm_bf<<<(N + 3) / 4, 256, 0, stream>>>(row_ptr, ccol, cw, cur_in, agg_bf, N);
    dense_mfma<<<Npad / 128, 256, 0, stream>>>(
        agg_bf, W_bf + (size_t)i * D * D, gcn_b + (size_t)i * D, enc_bf, N);
    cur_in = enc_bf;
  }

  // gathers + attention (f32)
  gather_bf_to_f32<<<BL, 128, 0, stream>>>(enc_bf, x_idx, geo, BL);
  gather_bf_to_f32<<<B, 128, 0, stream>>>(enc_bf, poi_idx, out + (size_t)B * D, B);
  qkv_kernel<<<(BL + 15) / 16, 384, 0, stream>>>(geo, in_w, in_b, qkv, BL);
  attn_kernel<<<B * HEADS, 128, 0, stream>>>(qkv, obuf);
  out_mean_kernel<<<B, 128, 0, stream>>>(obuf, out_w, out_b, out, L);
}

// Round 5
// 380.866 us; speedup vs baseline: 2.4054x; 1.3599x over previous
//
#include <hip/hip_runtime.h>
#include <math.h>

#define D 128
#define GCN_NUM 3
#define HEADS 8
#define HD 16
#define L_SEQ 100
#define LEAKY 0.01f

typedef __attribute__((ext_vector_type(8))) short short8v;
typedef __attribute__((ext_vector_type(4))) float f32x4;

__device__ __forceinline__ unsigned f2bf(float x) {
  unsigned u = __float_as_uint(x);
  return (u + 0x7FFFu + ((u >> 16) & 1u)) >> 16;
}
__device__ __forceinline__ float bflo2f(unsigned u) {  // low ushort -> float
  return __uint_as_float(u << 16);
}
__device__ __forceinline__ float bfhi2f(unsigned u) {  // high ushort -> float
  return __uint_as_float(u & 0xFFFF0000u);
}

// ---------------- dtype convert ----------------

__global__ void f32_to_bf16_kernel(const float* __restrict__ src,
                                   unsigned short* __restrict__ dst, int n4) {
  int i = blockIdx.x * blockDim.x + threadIdx.x;
  if (i < n4) {
    float4 v = reinterpret_cast<const float4*>(src)[i];
    uint2 o;
    o.x = f2bf(v.x) | (f2bf(v.y) << 16);
    o.y = f2bf(v.z) | (f2bf(v.w) << 16);
    reinterpret_cast<uint2*>(dst)[i] = o;
  }
}

// ---------------- graph build ----------------

__global__ void fill_deg(int* __restrict__ deg, int n) {
  int i = blockIdx.x * blockDim.x + threadIdx.x;
  if (i < n) deg[i] = 1;  // self-loop
}

__global__ void count_deg(const int* __restrict__ e0, const int* __restrict__ e1,
                          int* __restrict__ deg, int E) {
  int stride = gridDim.x * blockDim.x;
  for (int i = blockIdx.x * blockDim.x + threadIdx.x; i < E; i += stride) {
    atomicAdd(&deg[e0[i]], 1);
    atomicAdd(&deg[e1[i]], 1);
  }
}

// ---- parallel exclusive scan over deg (3 small kernels; N<=64*1024) ----

__global__ __launch_bounds__(1024) void block_sum(const int* __restrict__ deg,
                                                  int* __restrict__ bsum, int n) {
  __shared__ int ws[16];
  int tid = threadIdx.x, lane = tid & 63, wid = tid >> 6;
  int i = blockIdx.x * 1024 + tid;
  int v = (i < n) ? deg[i] : 0;
#pragma unroll
  for (int off = 32; off; off >>= 1) v += __shfl_xor(v, off);
  if (lane == 0) ws[wid] = v;
  __syncthreads();
  if (tid == 0) {
    int s = 0;
#pragma unroll
    for (int k = 0; k < 16; ++k) s += ws[k];
    bsum[blockIdx.x] = s;
  }
}

// single wave: exclusive scan of nb (<=64) block sums; writes grand total
__global__ void scan_bsum(int* __restrict__ bsum, int* __restrict__ total_out, int nb) {
  int tid = threadIdx.x;
  int v = (tid < nb) ? bsum[tid] : 0;
  int x = v;
#pragma unroll
  for (int off = 1; off < 64; off <<= 1) {
    int y = __shfl_up(x, off);
    if (tid >= off) x += y;
  }
  if (tid < nb) bsum[tid] = x - v;  // exclusive
  if (tid == 63) *total_out = x;    // grand total
}

__global__ __launch_bounds__(1024) void scan_final(
    const int* __restrict__ deg, const int* __restrict__ bsum,
    int* __restrict__ row_ptr, int* __restrict__ cursor, int n) {
  __shared__ int ws[16];
  int tid = threadIdx.x, lane = tid & 63, wid = tid >> 6;
  int i = blockIdx.x * 1024 + tid;
  int v = (i < n) ? deg[i] : 0;
  int x = v;
#pragma unroll
  for (int off = 1; off < 64; off <<= 1) {
    int y = __shfl_up(x, off);
    if (lane >= off) x += y;
  }
  if (lane == 63) ws[wid] = x;
  __syncthreads();
  if (wid == 0) {
    int s = (lane < 16) ? ws[lane] : 0;
#pragma unroll
    for (int off = 1; off < 16; off <<= 1) {
      int y = __shfl_up(s, off);
      if (lane >= off) s += y;
    }
    if (lane < 16) ws[lane] = s;  // inclusive over waves
  }
  __syncthreads();
  int woff = wid ? ws[wid - 1] : 0;
  if (i < n) {
    int pval = bsum[blockIdx.x] + woff + (x - v);
    row_ptr[i] = pval;
    cursor[i] = pval;
  }
}

// scatter: packed (col, weight) as uint2; dis = rsqrt(deg) fused inline
__global__ void scatter_edges(const int* __restrict__ e0, const int* __restrict__ e1,
                              const float* __restrict__ dv, const int* __restrict__ deg,
                              int* __restrict__ cursor, uint2* __restrict__ ecw,
                              int E, int N) {
  int total = 2 * E + N;
  int stride = gridDim.x * blockDim.x;
  for (int i = blockIdx.x * blockDim.x + threadIdx.x; i < total; i += stride) {
    int r, c; float d;
    if (i < E)          { r = e0[i];     c = e1[i];     d = dv[i]; }
    else if (i < 2 * E) { r = e1[i - E]; c = e0[i - E]; d = dv[i - E]; }
    else                { r = i - 2 * E; c = r;         d = 0.f; }
    float w = expf(-d * d) * (1.0f / sqrtf((float)deg[r])) * (1.0f / sqrtf((float)deg[c]));
    int pos = atomicAdd(&cursor[r], 1);
    ecw[pos] = make_uint2((unsigned)c, __float_as_uint(w));
  }
}

// ---------------- GCN ----------------

// SpMM: one row per wave, 4 edge-groups of 16 lanes each (4 gathers in flight).
// Lane (g,t): group g handles edges s+g, s+g+4, ...; lane covers features t*8..t*8+7.
__global__ __launch_bounds__(256) void spmm_bf(
    const int* __restrict__ row_ptr, const uint2* __restrict__ ecw,
    const unsigned short* __restrict__ enc, unsigned short* __restrict__ agg, int n) {
  int r = blockIdx.x * 4 + (threadIdx.x >> 6);
  if (r >= n) return;
  int lane = threadIdx.x & 63;
  int g = lane >> 4, t = lane & 15;
  int s = row_ptr[r], e = row_ptr[r + 1];
  float a0 = 0.f, a1 = 0.f, a2 = 0.f, a3 = 0.f, a4 = 0.f, a5 = 0.f, a6 = 0.f, a7 = 0.f;
  int i = s + g;
  uint2 cw = make_uint2(0u, 0u);
  if (i < e) cw = ecw[i];
  while (i < e) {
    int c = (int)cw.x;
    float wv = __uint_as_float(cw.y);
    int inx = i + 4;
    uint2 nxt = cw;
    if (inx < e) nxt = ecw[inx];  // prefetch next edge descriptor
    uint4 u = *reinterpret_cast<const uint4*>(enc + (size_t)c * D + t * 8);
    a0 = fmaf(wv, bflo2f(u.x), a0); a1 = fmaf(wv, bfhi2f(u.x), a1);
    a2 = fmaf(wv, bflo2f(u.y), a2); a3 = fmaf(wv, bfhi2f(u.y), a3);
    a4 = fmaf(wv, bflo2f(u.z), a4); a5 = fmaf(wv, bfhi2f(u.z), a5);
    a6 = fmaf(wv, bflo2f(u.w), a6); a7 = fmaf(wv, bfhi2f(u.w), a7);
    cw = nxt; i = inx;
  }
  // reduce across the 4 groups (lanes xor 16, 32)
  a0 += __shfl_xor(a0, 16); a0 += __shfl_xor(a0, 32);
  a1 += __shfl_xor(a1, 16); a1 += __shfl_xor(a1, 32);
  a2 += __shfl_xor(a2, 16); a2 += __shfl_xor(a2, 32);
  a3 += __shfl_xor(a3, 16); a3 += __shfl_xor(a3, 32);
  a4 += __shfl_xor(a4, 16); a4 += __shfl_xor(a4, 32);
  a5 += __shfl_xor(a5, 16); a5 += __shfl_xor(a5, 32);
  a6 += __shfl_xor(a6, 16); a6 += __shfl_xor(a6, 32);
  a7 += __shfl_xor(a7, 16); a7 += __shfl_xor(a7, 32);
  if (g == 0) {
    uint4 o;
    o.x = f2bf(a0) | (f2bf(a1) << 16);
    o.y = f2bf(a2) | (f2bf(a3) << 16);
    o.z = f2bf(a4) | (f2bf(a5) << 16);
    o.w = f2bf(a6) | (f2bf(a7) << 16);
    *reinterpret_cast<uint4*>(agg + (size_t)r * D + t * 8) = o;
  }
}

// enc = normalize(leaky_relu(A @ W^T + b)) via MFMA bf16.
// 256 threads = 4 waves; block covers 128 rows (2 row-tiles of 16 per wave).
__global__ __launch_bounds__(256) void dense_mfma(
    const unsigned short* __restrict__ A,    // [Npad][128] bf16
    const unsigned short* __restrict__ Wb,   // [128 out][128 in] bf16
    const float* __restrict__ bias,
    unsigned short* __restrict__ enc,        // [Npad][128] bf16
    int n) {
  __shared__ unsigned short Wl[128 * 136];   // padded stride: 272 B
  int tid = threadIdx.x;
  {
    int cg = (tid & 15) * 8;
    int r0 = tid >> 4;
#pragma unroll
    for (int i = 0; i < 8; ++i) {
      int row = r0 + i * 16;
      *reinterpret_cast<short8v*>(&Wl[row * 136 + cg]) =
          *reinterpret_cast<const short8v*>(Wb + row * D + cg);
    }
  }
  __syncthreads();
  int w = tid >> 6, lane = tid & 63;
  int lr = lane & 15, lg = lane >> 4;
#pragma unroll
  for (int rt = 0; rt < 2; ++rt) {
    int rbase = blockIdx.x * 128 + rt * 64 + w * 16;
    f32x4 acc[8];
#pragma unroll
    for (int j = 0; j < 8; ++j) acc[j] = f32x4{0.f, 0.f, 0.f, 0.f};
    const unsigned short* arow = A + (size_t)(rbase + lr) * D + lg * 8;
#pragma unroll
    for (int ks = 0; ks < 4; ++ks) {
      short8v a = *reinterpret_cast<const short8v*>(arow + ks * 32);
#pragma unroll
      for (int jt = 0; jt < 8; ++jt) {
        short8v b = *reinterpret_cast<const short8v*>(&Wl[(jt * 16 + lr) * 136 + ks * 32 + lg * 8]);
        acc[jt] = __builtin_amdgcn_mfma_f32_16x16x32_bf16(a, b, acc[jt], 0, 0, 0);
      }
    }
    float vals[8][4];
    float ss[4] = {0.f, 0.f, 0.f, 0.f};
#pragma unroll
    for (int jt = 0; jt < 8; ++jt) {
      float bj = bias[jt * 16 + lr];
#pragma unroll
      for (int i = 0; i < 4; ++i) {
        float t = acc[jt][i] + bj;
        t = (t > 0.f) ? t : LEAKY * t;
        vals[jt][i] = t;
        ss[i] += t * t;
      }
    }
#pragma unroll
    for (int i = 0; i < 4; ++i) {
      float s = ss[i];
      s += __shfl_xor(s, 1); s += __shfl_xor(s, 2);
      s += __shfl_xor(s, 4); s += __shfl_xor(s, 8);
      ss[i] = 1.0f / fmaxf(sqrtf(s), 1e-12f);
    }
#pragma unroll
    for (int i = 0; i < 4; ++i) {
      int row = rbase + lg * 4 + i;
      if (row < n) {
#pragma unroll
        for (int jt = 0; jt < 8; ++jt)
          enc[(size_t)row * D + jt * 16 + lr] = (unsigned short)f2bf(vals[jt][i] * ss[i]);
      }
    }
  }
}

// ---------------- gather + attention ----------------

// bf16 row copy gather (64 threads: one uint = 2 bf16 per lane)
__global__ void gather_bf(const unsigned short* __restrict__ src,
                          const int* __restrict__ idx,
                          unsigned short* __restrict__ dst, int M) {
  int i = blockIdx.x;
  if (i < M) {
    int t = threadIdx.x;
    reinterpret_cast<unsigned*>(dst + (size_t)i * D)[t] =
        reinterpret_cast<const unsigned*>(src + (size_t)idx[i] * D)[t];
  }
}

__global__ void gather_bf_to_f32(const unsigned short* __restrict__ src,
                                 const int* __restrict__ idx,
                                 float* __restrict__ dst, int M) {
  int i = blockIdx.x;
  if (i < M) {
    int t = threadIdx.x;
    dst[(size_t)i * D + t] = bflo2f(src[(size_t)idx[i] * D + t]);
  }
}

// qkv via MFMA: grid (M/128, 3); blockIdx.y selects the q/k/v third of in_w.
__global__ __launch_bounds__(256) void qkv_mfma(
    const unsigned short* __restrict__ A,    // [M][128] bf16 (geo)
    const unsigned short* __restrict__ Wb,   // [384][128] bf16
    const float* __restrict__ bias,          // [384]
    float* __restrict__ qkv, int M) {
  __shared__ unsigned short Wl[128 * 136];
  int tid = threadIdx.x;
  const unsigned short* Wslab = Wb + (size_t)blockIdx.y * 128 * D;
  {
    int cg = (tid & 15) * 8;
    int r0 = tid >> 4;
#pragma unroll
    for (int i = 0; i < 8; ++i) {
      int row = r0 + i * 16;
      *reinterpret_cast<short8v*>(&Wl[row * 136 + cg]) =
          *reinterpret_cast<const short8v*>(Wslab + row * D + cg);
    }
  }
  __syncthreads();
  int w = tid >> 6, lane = tid & 63;
  int lr = lane & 15, lg = lane >> 4;
  int colbase = blockIdx.y * 128;
#pragma unroll
  for (int rt = 0; rt < 2; ++rt) {
    int rbase = blockIdx.x * 128 + rt * 64 + w * 16;
    f32x4 acc[8];
#pragma unroll
    for (int j = 0; j < 8; ++j) acc[j] = f32x4{0.f, 0.f, 0.f, 0.f};
    const unsigned short* arow = A + (size_t)(rbase + lr) * D + lg * 8;
#pragma unroll
    for (int ks = 0; ks < 4; ++ks) {
      short8v a = *reinterpret_cast<const short8v*>(arow + ks * 32);
#pragma unroll
      for (int jt = 0; jt < 8; ++jt) {
        short8v b = *reinterpret_cast<const short8v*>(&Wl[(jt * 16 + lr) * 136 + ks * 32 + lg * 8]);
        acc[jt] = __builtin_amdgcn_mfma_f32_16x16x32_bf16(a, b, acc[jt], 0, 0, 0);
      }
    }
#pragma unroll
    for (int jt = 0; jt < 8; ++jt) {
      int j = colbase + jt * 16 + lr;
      float bj = bias[j];
#pragma unroll
      for (int i = 0; i < 4; ++i) {
        int row = rbase + lg * 4 + i;
        if (row < M) qkv[(size_t)row * 384 + j] = acc[jt][i] + bj;
      }
    }
  }
}

__global__ __launch_bounds__(128) void attn_kernel(
    const float* __restrict__ qkv, float* __restrict__ o) {
  __shared__ float k_s[L_SEQ][HD];
  __shared__ float v_s[L_SEQ][HD];
  __shared__ float sc[L_SEQ][L_SEQ + 1];
  int b = blockIdx.x / HEADS;
  int h = blockIdx.x % HEADS;
  int tid = threadIdx.x;
  const size_t rowbase = (size_t)b * L_SEQ;
  for (int idx = tid; idx < L_SEQ * HD; idx += 128) {
    int l = idx >> 4, d2 = idx & 15;
    const float* base = qkv + (rowbase + l) * 384 + h * HD + d2;
    k_s[l][d2] = base[128];
    v_s[l][d2] = base[256];
  }
  __syncthreads();
  if (tid < L_SEQ) {
    float q[HD];
    const float* qp = qkv + (rowbase + tid) * 384 + h * HD;
#pragma unroll
    for (int d2 = 0; d2 < HD; ++d2) q[d2] = qp[d2];
    float m = -1e30f;
    for (int j = 0; j < L_SEQ; ++j) {
      float s = 0.f;
#pragma unroll
      for (int d2 = 0; d2 < HD; ++d2) s += q[d2] * k_s[j][d2];
      s *= 0.25f;
      sc[tid][j] = s;
      m = fmaxf(m, s);
    }
    float sum = 0.f;
    for (int j = 0; j < L_SEQ; ++j) {
      float e = expf(sc[tid][j] - m);
      sc[tid][j] = e;
      sum += e;
    }
    float inv = 1.f / sum;
    float oacc[HD];
#pragma unroll
    for (int d2 = 0; d2 < HD; ++d2) oacc[d2] = 0.f;
    for (int j = 0; j < L_SEQ; ++j) {
      float p = sc[tid][j];
#pragma unroll
      for (int d2 = 0; d2 < HD; ++d2) oacc[d2] += p * v_s[j][d2];
    }
    float* op = o + (rowbase + tid) * D + h * HD;
#pragma unroll
    for (int d2 = 0; d2 < HD; ++d2) op[d2] = oacc[d2] * inv;
  }
}

__global__ __launch_bounds__(128) void out_mean_kernel(
    const float* __restrict__ o, const float* __restrict__ Wo,
    const float* __restrict__ bo, float* __restrict__ out, int L) {
  __shared__ float m_s[D];
  int b = blockIdx.x, tid = threadIdx.x;
  float s = 0.f;
  for (int l = 0; l < L; ++l) s += o[((size_t)b * L + l) * D + tid];
  m_s[tid] = s / (float)L;
  __syncthreads();
  const float4* w4 = reinterpret_cast<const float4*>(Wo + (size_t)tid * D);
  float acc = 0.f;
  for (int k4 = 0; k4 < D / 4; ++k4) {
    float4 w = w4[k4];
    int k = k4 * 4;
    acc += m_s[k] * w.x + m_s[k + 1] * w.y + m_s[k + 2] * w.z + m_s[k + 3] * w.w;
  }
  out[(size_t)b * D + tid] = acc + bo[tid];
}

// ---------------- launch ----------------

extern "C" void kernel_launch(void* const* d_in, const int* in_sizes, int n_in,
                              void* d_out, int out_size, void* d_ws, size_t ws_size,
                              hipStream_t stream) {
  const float* embeds   = (const float*)d_in[0];
  const float* gcn_W    = (const float*)d_in[1];
  const float* gcn_b    = (const float*)d_in[2];
  const float* in_w     = (const float*)d_in[3];
  const float* in_b     = (const float*)d_in[4];
  const float* out_w    = (const float*)d_in[5];
  const float* out_b    = (const float*)d_in[6];
  const float* dist_vec = (const float*)d_in[7];
  const int*   edges    = (const int*)d_in[8];
  const int*   x_idx    = (const int*)d_in[9];
  const int*   poi_idx  = (const int*)d_in[10];
  float* out = (float*)d_out;

  int N  = in_sizes[0] / D;   // 50000
  int E  = in_sizes[7];       // 400000
  int BL = in_sizes[9];       // 6400
  int B  = in_sizes[10];      // 64
  int L  = BL / B;            // 100
  const int* e0 = edges;
  const int* e1 = edges + E;
  size_t total_edges = (size_t)2 * E + N;          // 850000
  int Npad = ((N + 127) / 128) * 128;              // 50048
  int NB   = (N + 1023) / 1024;                    // 49 (must be <= 64)

  char* p = (char*)d_ws;
  auto alloc = [&](size_t bytes) { char* q = p; p += (bytes + 255) & ~(size_t)255; return q; };
  int*   deg     = (int*)alloc((size_t)N * 4);
  int*   row_ptr = (int*)alloc((size_t)(N + 1) * 4);
  int*   cursor  = (int*)alloc((size_t)N * 4);
  int*   bsum    = (int*)alloc((size_t)NB * 4);
  uint2* ecw     = (uint2*)alloc(total_edges * 8);
  unsigned short* emb_bf = (unsigned short*)alloc((size_t)Npad * D * 2);
  unsigned short* W_bf   = (unsigned short*)alloc((size_t)GCN_NUM * D * D * 2);
  unsigned short* inw_bf = (unsigned short*)alloc((size_t)3 * D * D * 2);
  unsigned short* agg_bf = (unsigned short*)alloc((size_t)Npad * D * 2);
  unsigned short* enc_bf = (unsigned short*)alloc((size_t)Npad * D * 2);
  unsigned short* geo_bf = (unsigned short*)alloc((size_t)BL * D * 2);
  float* qkv  = (float*)alloc((size_t)BL * 384 * 4);
  float* obuf = (float*)alloc((size_t)BL * D * 4);

  // convert inputs to bf16
  int n4e = N * D / 4;
  f32_to_bf16_kernel<<<(n4e + 255) / 256, 256, 0, stream>>>(embeds, emb_bf, n4e);
  int n4w = GCN_NUM * D * D / 4;
  f32_to_bf16_kernel<<<(n4w + 255) / 256, 256, 0, stream>>>(gcn_W, W_bf, n4w);
  int n4i = 3 * D * D / 4;
  f32_to_bf16_kernel<<<(n4i + 255) / 256, 256, 0, stream>>>(in_w, inw_bf, n4i);

  // graph build
  fill_deg<<<(N + 255) / 256, 256, 0, stream>>>(deg, N);
  count_deg<<<1024, 256, 0, stream>>>(e0, e1, deg, E);
  block_sum<<<NB, 1024, 0, stream>>>(deg, bsum, N);
  scan_bsum<<<1, 64, 0, stream>>>(bsum, row_ptr + N, NB);
  scan_final<<<NB, 1024, 0, stream>>>(deg, bsum, row_ptr, cursor, N);
  scatter_edges<<<2048, 256, 0, stream>>>(e0, e1, dist_vec, deg, cursor, ecw, E, N);

  // GCN layers (bf16 storage, MFMA dense)
  const unsigned short* cur_in = emb_bf;
  for (int i = 0; i < GCN_NUM; ++i) {
    spmm_bf<<<(N + 3) / 4, 256, 0, stream>>>(row_ptr, ecw, cur_in, agg_bf, N);
    dense_mfma<<<Npad / 128, 256, 0, stream>>>(
        agg_bf, W_bf + (size_t)i * D * D, gcn_b + (size_t)i * D, enc_bf, N);
    cur_in = enc_bf;
  }

  // gathers + attention
  gather_bf<<<BL, 64, 0, stream>>>(enc_bf, x_idx, geo_bf, BL);
  gather_bf_to_f32<<<B, 128, 0, stream>>>(enc_bf, poi_idx, out + (size_t)B * D, B);
  dim3 qgrid(BL / 128, 3);
  qkv_mfma<<<qgrid, 256, 0, stream>>>(geo_bf, inw_bf, in_b, qkv, BL);
  attn_kernel<<<B * HEADS, 128, 0, stream>>>(qkv, obuf);
  out_mean_kernel<<<B, 128, 0, stream>>>(obuf, out_w, out_b, out, L);
}

// Round 6
// 370.085 us; speedup vs baseline: 2.4754x; 1.0291x over previous
//
#include <hip/hip_runtime.h>
#include <math.h>

#define D 128
#define GCN_NUM 3
#define HEADS 8
#define HD 16
#define L_SEQ 100
#define LEAKY 0.01f
#define SC_BUCKETS 8

typedef __attribute__((ext_vector_type(8))) short short8v;
typedef __attribute__((ext_vector_type(4))) float f32x4;

__device__ __forceinline__ unsigned f2bf(float x) {
  unsigned u = __float_as_uint(x);
  return (u + 0x7FFFu + ((u >> 16) & 1u)) >> 16;
}
__device__ __forceinline__ float bflo2f(unsigned u) { return __uint_as_float(u << 16); }
__device__ __forceinline__ float bfhi2f(unsigned u) { return __uint_as_float(u & 0xFFFF0000u); }

// ---------------- fused dtype convert (3 segments) ----------------

__global__ void convert3(const float* __restrict__ s0, unsigned short* __restrict__ d0, int n0,
                         const float* __restrict__ s1, unsigned short* __restrict__ d1, int n1,
                         const float* __restrict__ s2, unsigned short* __restrict__ d2, int n2) {
  int i = blockIdx.x * blockDim.x + threadIdx.x;
  const float* s; unsigned short* d; int j;
  if (i < n0)            { s = s0; d = d0; j = i; }
  else if (i < n0 + n1)  { s = s1; d = d1; j = i - n0; }
  else if (i < n0 + n1 + n2) { s = s2; d = d2; j = i - n0 - n1; }
  else return;
  float4 v = reinterpret_cast<const float4*>(s)[j];
  uint2 o;
  o.x = f2bf(v.x) | (f2bf(v.y) << 16);
  o.y = f2bf(v.z) | (f2bf(v.w) << 16);
  reinterpret_cast<uint2*>(d)[j] = o;
}

// ---------------- graph build ----------------

__global__ void fill_deg(int* __restrict__ deg, int n) {
  int i = blockIdx.x * blockDim.x + threadIdx.x;
  if (i < n) deg[i] = 1;  // self-loop
}

__global__ void count_deg(const int* __restrict__ e0, const int* __restrict__ e1,
                          int* __restrict__ deg, int E) {
  int stride = gridDim.x * blockDim.x;
  for (int i = blockIdx.x * blockDim.x + threadIdx.x; i < E; i += stride) {
    atomicAdd(&deg[e0[i]], 1);
    atomicAdd(&deg[e1[i]], 1);
  }
}

// ---- parallel exclusive scan over deg (2 kernels; NB <= 64) ----

__global__ __launch_bounds__(1024) void block_sum(const int* __restrict__ deg,
                                                  int* __restrict__ bsum, int n) {
  __shared__ int ws[16];
  int tid = threadIdx.x, lane = tid & 63, wid = tid >> 6;
  int i = blockIdx.x * 1024 + tid;
  int v = (i < n) ? deg[i] : 0;
#pragma unroll
  for (int off = 32; off; off >>= 1) v += __shfl_xor(v, off);
  if (lane == 0) ws[wid] = v;
  __syncthreads();
  if (tid == 0) {
    int s = 0;
#pragma unroll
    for (int k = 0; k < 16; ++k) s += ws[k];
    bsum[blockIdx.x] = s;
  }
}

// each block derives its own prefix from raw bsum (NB<=64); last block writes total
__global__ __launch_bounds__(1024) void scan_final(
    const int* __restrict__ deg, const int* __restrict__ bsum,
    int* __restrict__ row_ptr, int* __restrict__ cursor, int n, int nb) {
  __shared__ int ws[16];
  __shared__ int prefix_s;
  int tid = threadIdx.x, lane = tid & 63, wid = tid >> 6;
  int i = blockIdx.x * 1024 + tid;
  int v = (i < n) ? deg[i] : 0;
  int x = v;
#pragma unroll
  for (int off = 1; off < 64; off <<= 1) {
    int y = __shfl_up(x, off);
    if (lane >= off) x += y;
  }
  if (lane == 63) ws[wid] = x;
  __syncthreads();
  if (wid == 0) {
    // prefix of earlier blocks
    int pv = (lane < blockIdx.x) ? bsum[lane] : 0;
#pragma unroll
    for (int off = 32; off; off >>= 1) pv += __shfl_xor(pv, off);
    if (lane == 0) prefix_s = pv;
    // scan wave sums
    int s = (lane < 16) ? ws[lane] : 0;
#pragma unroll
    for (int off = 1; off < 16; off <<= 1) {
      int y = __shfl_up(s, off);
      if (lane >= off) s += y;
    }
    if (lane < 16) ws[lane] = s;  // inclusive over waves
  }
  __syncthreads();
  int woff = wid ? ws[wid - 1] : 0;
  int prefix = prefix_s;
  if (i < n) {
    int pval = prefix + woff + (x - v);
    row_ptr[i] = pval;
    cursor[i] = pval;
  }
  if (blockIdx.x == nb - 1 && tid == 0) row_ptr[n] = prefix + ws[15];
}

// bucketed scatter: bucket = blockIdx.x / bpb owns row range [rlo, rhi);
// writes cluster into a contiguous ~850KB ecw region per bucket -> full-line writes
__global__ __launch_bounds__(256) void scatter_edges_b(
    const int* __restrict__ e0, const int* __restrict__ e1,
    const float* __restrict__ dv, const int* __restrict__ deg,
    int* __restrict__ cursor, uint2* __restrict__ ecw,
    int E, int N, int span, int bpb) {
  int bucket = blockIdx.x / bpb;
  int bx = blockIdx.x % bpb;
  int rlo = bucket * span;
  int rhi = min(rlo + span, N);
  int total = 2 * E + N;
  int stride = bpb * 256;
  for (int i = bx * 256 + threadIdx.x; i < total; i += stride) {
    int r, c; bool self = false;
    if (i < E)          { r = e0[i];     c = e1[i]; }
    else if (i < 2 * E) { r = e1[i - E]; c = e0[i - E]; }
    else                { r = i - 2 * E; c = r; self = true; }
    if (r < rlo || r >= rhi) continue;
    float d = self ? 0.f : dv[(i < E) ? i : i - E];
    float w = expf(-d * d) * (1.0f / sqrtf((float)deg[r])) * (1.0f / sqrtf((float)deg[c]));
    int pos = atomicAdd(&cursor[r], 1);
    ecw[pos] = make_uint2((unsigned)c, __float_as_uint(w));
  }
}

// ---------------- GCN ----------------

// SpMM: one row per wave, 4 edge-groups of 16 lanes, 2-deep pipeline per group
// (2 row gathers + 2 descriptor prefetches in flight -> 16 loads/wave).
__global__ __launch_bounds__(256) void spmm_bf(
    const int* __restrict__ row_ptr, const uint2* __restrict__ ecw,
    const unsigned short* __restrict__ enc, unsigned short* __restrict__ agg, int n) {
  int r = blockIdx.x * 4 + (threadIdx.x >> 6);
  if (r >= n) return;
  int lane = threadIdx.x & 63;
  int g = lane >> 4, t = lane & 15;
  int s = row_ptr[r], e = row_ptr[r + 1];
  float a0 = 0.f, a1 = 0.f, a2 = 0.f, a3 = 0.f, a4 = 0.f, a5 = 0.f, a6 = 0.f, a7 = 0.f;
  int i = s + g;  // this group's edges: i, i+4, i+8, ...
  uint2 cwA = make_uint2(0u, 0u), cwB = make_uint2(0u, 0u);
  if (i < e) cwA = ecw[i];
  if (i + 4 < e) cwB = ecw[i + 4];
  while (i + 4 < e) {
    uint2 cwC = cwA, cwD = cwB;
    if (i + 8 < e)  cwC = ecw[i + 8];
    if (i + 12 < e) cwD = ecw[i + 12];
    float wA = __uint_as_float(cwA.y), wB = __uint_as_float(cwB.y);
    uint4 uA = *reinterpret_cast<const uint4*>(enc + (size_t)cwA.x * D + t * 8);
    uint4 uB = *reinterpret_cast<const uint4*>(enc + (size_t)cwB.x * D + t * 8);
    a0 = fmaf(wA, bflo2f(uA.x), a0); a1 = fmaf(wA, bfhi2f(uA.x), a1);
    a2 = fmaf(wA, bflo2f(uA.y), a2); a3 = fmaf(wA, bfhi2f(uA.y), a3);
    a4 = fmaf(wA, bflo2f(uA.z), a4); a5 = fmaf(wA, bfhi2f(uA.z), a5);
    a6 = fmaf(wA, bflo2f(uA.w), a6); a7 = fmaf(wA, bfhi2f(uA.w), a7);
    a0 = fmaf(wB, bflo2f(uB.x), a0); a1 = fmaf(wB, bfhi2f(uB.x), a1);
    a2 = fmaf(wB, bflo2f(uB.y), a2); a3 = fmaf(wB, bfhi2f(uB.y), a3);
    a4 = fmaf(wB, bflo2f(uB.z), a4); a5 = fmaf(wB, bfhi2f(uB.z), a5);
    a6 = fmaf(wB, bflo2f(uB.w), a6); a7 = fmaf(wB, bfhi2f(uB.w), a7);
    cwA = cwC; cwB = cwD;
    i += 8;
  }
  if (i < e) {  // at most one leftover edge (cwA)
    float wA = __uint_as_float(cwA.y);
    uint4 uA = *reinterpret_cast<const uint4*>(enc + (size_t)cwA.x * D + t * 8);
    a0 = fmaf(wA, bflo2f(uA.x), a0); a1 = fmaf(wA, bfhi2f(uA.x), a1);
    a2 = fmaf(wA, bflo2f(uA.y), a2); a3 = fmaf(wA, bfhi2f(uA.y), a3);
    a4 = fmaf(wA, bflo2f(uA.z), a4); a5 = fmaf(wA, bfhi2f(uA.z), a5);
    a6 = fmaf(wA, bflo2f(uA.w), a6); a7 = fmaf(wA, bfhi2f(uA.w), a7);
  }
  a0 += __shfl_xor(a0, 16); a0 += __shfl_xor(a0, 32);
  a1 += __shfl_xor(a1, 16); a1 += __shfl_xor(a1, 32);
  a2 += __shfl_xor(a2, 16); a2 += __shfl_xor(a2, 32);
  a3 += __shfl_xor(a3, 16); a3 += __shfl_xor(a3, 32);
  a4 += __shfl_xor(a4, 16); a4 += __shfl_xor(a4, 32);
  a5 += __shfl_xor(a5, 16); a5 += __shfl_xor(a5, 32);
  a6 += __shfl_xor(a6, 16); a6 += __shfl_xor(a6, 32);
  a7 += __shfl_xor(a7, 16); a7 += __shfl_xor(a7, 32);
  if (g == 0) {
    uint4 o;
    o.x = f2bf(a0) | (f2bf(a1) << 16);
    o.y = f2bf(a2) | (f2bf(a3) << 16);
    o.z = f2bf(a4) | (f2bf(a5) << 16);
    o.w = f2bf(a6) | (f2bf(a7) << 16);
    *reinterpret_cast<uint4*>(agg + (size_t)r * D + t * 8) = o;
  }
}

// enc = normalize(leaky_relu(A @ W^T + b)) via MFMA bf16.
__global__ __launch_bounds__(256) void dense_mfma(
    const unsigned short* __restrict__ A, const unsigned short* __restrict__ Wb,
    const float* __restrict__ bias, unsigned short* __restrict__ enc, int n) {
  __shared__ unsigned short Wl[128 * 136];
  int tid = threadIdx.x;
  {
    int cg = (tid & 15) * 8;
    int r0 = tid >> 4;
#pragma unroll
    for (int i = 0; i < 8; ++i) {
      int row = r0 + i * 16;
      *reinterpret_cast<short8v*>(&Wl[row * 136 + cg]) =
          *reinterpret_cast<const short8v*>(Wb + row * D + cg);
    }
  }
  __syncthreads();
  int w = tid >> 6, lane = tid & 63;
  int lr = lane & 15, lg = lane >> 4;
#pragma unroll
  for (int rt = 0; rt < 2; ++rt) {
    int rbase = blockIdx.x * 128 + rt * 64 + w * 16;
    f32x4 acc[8];
#pragma unroll
    for (int j = 0; j < 8; ++j) acc[j] = f32x4{0.f, 0.f, 0.f, 0.f};
    const unsigned short* arow = A + (size_t)(rbase + lr) * D + lg * 8;
#pragma unroll
    for (int ks = 0; ks < 4; ++ks) {
      short8v a = *reinterpret_cast<const short8v*>(arow + ks * 32);
#pragma unroll
      for (int jt = 0; jt < 8; ++jt) {
        short8v b = *reinterpret_cast<const short8v*>(&Wl[(jt * 16 + lr) * 136 + ks * 32 + lg * 8]);
        acc[jt] = __builtin_amdgcn_mfma_f32_16x16x32_bf16(a, b, acc[jt], 0, 0, 0);
      }
    }
    float vals[8][4];
    float ss[4] = {0.f, 0.f, 0.f, 0.f};
#pragma unroll
    for (int jt = 0; jt < 8; ++jt) {
      float bj = bias[jt * 16 + lr];
#pragma unroll
      for (int i = 0; i < 4; ++i) {
        float t = acc[jt][i] + bj;
        t = (t > 0.f) ? t : LEAKY * t;
        vals[jt][i] = t;
        ss[i] += t * t;
      }
    }
#pragma unroll
    for (int i = 0; i < 4; ++i) {
      float s = ss[i];
      s += __shfl_xor(s, 1); s += __shfl_xor(s, 2);
      s += __shfl_xor(s, 4); s += __shfl_xor(s, 8);
      ss[i] = 1.0f / fmaxf(sqrtf(s), 1e-12f);
    }
#pragma unroll
    for (int i = 0; i < 4; ++i) {
      int row = rbase + lg * 4 + i;
      if (row < n) {
#pragma unroll
        for (int jt = 0; jt < 8; ++jt)
          enc[(size_t)row * D + jt * 16 + lr] = (unsigned short)f2bf(vals[jt][i] * ss[i]);
      }
    }
  }
}

// ---------------- gather + attention ----------------

// fused gather: blocks [0,BL) copy bf16 rows to geo; blocks [BL,BL+B) write f32 tar rows
__global__ void gather_all(const unsigned short* __restrict__ src,
                           const int* __restrict__ x_idx, const int* __restrict__ poi_idx,
                           unsigned short* __restrict__ geo, float* __restrict__ tar,
                           int BL, int B) {
  int i = blockIdx.x;
  int t = threadIdx.x;  // 64 threads; lane covers 2 bf16
  if (i < BL) {
    reinterpret_cast<unsigned*>(geo + (size_t)i * D)[t] =
        reinterpret_cast<const unsigned*>(src + (size_t)x_idx[i] * D)[t];
  } else {
    int j = i - BL;
    unsigned u = reinterpret_cast<const unsigned*>(src + (size_t)poi_idx[j] * D)[t];
    reinterpret_cast<float2*>(tar + (size_t)j * D)[t] = make_float2(bflo2f(u), bfhi2f(u));
  }
}

// qkv via MFMA: grid (M/128, 3); blockIdx.y selects the q/k/v third of in_w.
__global__ __launch_bounds__(256) void qkv_mfma(
    const unsigned short* __restrict__ A, const unsigned short* __restrict__ Wb,
    const float* __restrict__ bias, float* __restrict__ qkv, int M) {
  __shared__ unsigned short Wl[128 * 136];
  int tid = threadIdx.x;
  const unsigned short* Wslab = Wb + (size_t)blockIdx.y * 128 * D;
  {
    int cg = (tid & 15) * 8;
    int r0 = tid >> 4;
#pragma unroll
    for (int i = 0; i < 8; ++i) {
      int row = r0 + i * 16;
      *reinterpret_cast<short8v*>(&Wl[row * 136 + cg]) =
          *reinterpret_cast<const short8v*>(Wslab + row * D + cg);
    }
  }
  __syncthreads();
  int w = tid >> 6, lane = tid & 63;
  int lr = lane & 15, lg = lane >> 4;
  int colbase = blockIdx.y * 128;
#pragma unroll
  for (int rt = 0; rt < 2; ++rt) {
    int rbase = blockIdx.x * 128 + rt * 64 + w * 16;
    f32x4 acc[8];
#pragma unroll
    for (int j = 0; j < 8; ++j) acc[j] = f32x4{0.f, 0.f, 0.f, 0.f};
    const unsigned short* arow = A + (size_t)(rbase + lr) * D + lg * 8;
#pragma unroll
    for (int ks = 0; ks < 4; ++ks) {
      short8v a = *reinterpret_cast<const short8v*>(arow + ks * 32);
#pragma unroll
      for (int jt = 0; jt < 8; ++jt) {
        short8v b = *reinterpret_cast<const short8v*>(&Wl[(jt * 16 + lr) * 136 + ks * 32 + lg * 8]);
        acc[jt] = __builtin_amdgcn_mfma_f32_16x16x32_bf16(a, b, acc[jt], 0, 0, 0);
      }
    }
#pragma unroll
    for (int jt = 0; jt < 8; ++jt) {
      int j = colbase + jt * 16 + lr;
      float bj = bias[j];
#pragma unroll
      for (int i = 0; i < 4; ++i) {
        int row = rbase + lg * 4 + i;
        if (row < M) qkv[(size_t)row * 384 + j] = acc[jt][i] + bj;
      }
    }
  }
}

__global__ __launch_bounds__(128) void attn_kernel(
    const float* __restrict__ qkv, float* __restrict__ o) {
  __shared__ float k_s[L_SEQ][HD];
  __shared__ float v_s[L_SEQ][HD];
  __shared__ float sc[L_SEQ][L_SEQ + 1];
  int b = blockIdx.x / HEADS;
  int h = blockIdx.x % HEADS;
  int tid = threadIdx.x;
  const size_t rowbase = (size_t)b * L_SEQ;
  for (int idx = tid; idx < L_SEQ * HD; idx += 128) {
    int l = idx >> 4, d2 = idx & 15;
    const float* base = qkv + (rowbase + l) * 384 + h * HD + d2;
    k_s[l][d2] = base[128];
    v_s[l][d2] = base[256];
  }
  __syncthreads();
  if (tid < L_SEQ) {
    float q[HD];
    const float* qp = qkv + (rowbase + tid) * 384 + h * HD;
#pragma unroll
    for (int d2 = 0; d2 < HD; ++d2) q[d2] = qp[d2];
    float m = -1e30f;
    for (int j = 0; j < L_SEQ; ++j) {
      float s = 0.f;
#pragma unroll
      for (int d2 = 0; d2 < HD; ++d2) s += q[d2] * k_s[j][d2];
      s *= 0.25f;
      sc[tid][j] = s;
      m = fmaxf(m, s);
    }
    float sum = 0.f;
    for (int j = 0; j < L_SEQ; ++j) {
      float e = expf(sc[tid][j] - m);
      sc[tid][j] = e;
      sum += e;
    }
    float inv = 1.f / sum;
    float oacc[HD];
#pragma unroll
    for (int d2 = 0; d2 < HD; ++d2) oacc[d2] = 0.f;
    for (int j = 0; j < L_SEQ; ++j) {
      float p = sc[tid][j];
#pragma unroll
      for (int d2 = 0; d2 < HD; ++d2) oacc[d2] += p * v_s[j][d2];
    }
    float* op = o + (rowbase + tid) * D + h * HD;
#pragma unroll
    for (int d2 = 0; d2 < HD; ++d2) op[d2] = oacc[d2] * inv;
  }
}

__global__ __launch_bounds__(128) void out_mean_kernel(
    const float* __restrict__ o, const float* __restrict__ Wo,
    const float* __restrict__ bo, float* __restrict__ out, int L) {
  __shared__ float m_s[D];
  int b = blockIdx.x, tid = threadIdx.x;
  float s = 0.f;
  for (int l = 0; l < L; ++l) s += o[((size_t)b * L + l) * D + tid];
  m_s[tid] = s / (float)L;
  __syncthreads();
  const float4* w4 = reinterpret_cast<const float4*>(Wo + (size_t)tid * D);
  float acc = 0.f;
  for (int k4 = 0; k4 < D / 4; ++k4) {
    float4 w = w4[k4];
    int k = k4 * 4;
    acc += m_s[k] * w.x + m_s[k + 1] * w.y + m_s[k + 2] * w.z + m_s[k + 3] * w.w;
  }
  out[(size_t)b * D + tid] = acc + bo[tid];
}

// ---------------- launch ----------------

extern "C" void kernel_launch(void* const* d_in, const int* in_sizes, int n_in,
                              void* d_out, int out_size, void* d_ws, size_t ws_size,
                              hipStream_t stream) {
  const float* embeds   = (const float*)d_in[0];
  const float* gcn_W    = (const float*)d_in[1];
  const float* gcn_b    = (const float*)d_in[2];
  const float* in_w     = (const float*)d_in[3];
  const float* in_b     = (const float*)d_in[4];
  const float* out_w    = (const float*)d_in[5];
  const float* out_b    = (const float*)d_in[6];
  const float* dist_vec = (const float*)d_in[7];
  const int*   edges    = (const int*)d_in[8];
  const int*   x_idx    = (const int*)d_in[9];
  const int*   poi_idx  = (const int*)d_in[10];
  float* out = (float*)d_out;

  int N  = in_sizes[0] / D;   // 50000
  int E  = in_sizes[7];       // 400000
  int BL = in_sizes[9];       // 6400
  int B  = in_sizes[10];      // 64
  int L  = BL / B;            // 100
  const int* e0 = edges;
  const int* e1 = edges + E;
  size_t total_edges = (size_t)2 * E + N;          // 850000
  int Npad = ((N + 127) / 128) * 128;              // 50048
  int NB   = (N + 1023) / 1024;                    // 49 (<= 64)

  char* p = (char*)d_ws;
  auto alloc = [&](size_t bytes) { char* q = p; p += (bytes + 255) & ~(size_t)255; return q; };
  int*   deg     = (int*)alloc((size_t)N * 4);
  int*   row_ptr = (int*)alloc((size_t)(N + 1) * 4);
  int*   cursor  = (int*)alloc((size_t)N * 4);
  int*   bsum    = (int*)alloc((size_t)NB * 4);
  uint2* ecw     = (uint2*)alloc(total_edges * 8);
  unsigned short* emb_bf = (unsigned short*)alloc((size_t)Npad * D * 2);
  unsigned short* W_bf   = (unsigned short*)alloc((size_t)GCN_NUM * D * D * 2);
  unsigned short* inw_bf = (unsigned short*)alloc((size_t)3 * D * D * 2);
  unsigned short* agg_bf = (unsigned short*)alloc((size_t)Npad * D * 2);
  unsigned short* enc_bf = (unsigned short*)alloc((size_t)Npad * D * 2);
  unsigned short* geo_bf = (unsigned short*)alloc((size_t)BL * D * 2);
  float* qkv  = (float*)alloc((size_t)BL * 384 * 4);
  float* obuf = (float*)alloc((size_t)BL * D * 4);

  // convert inputs to bf16 (fused)
  int n4e = N * D / 4, n4w = GCN_NUM * D * D / 4, n4i = 3 * D * D / 4;
  int n4tot = n4e + n4w + n4i;
  convert3<<<(n4tot + 255) / 256, 256, 0, stream>>>(
      embeds, emb_bf, n4e, gcn_W, W_bf, n4w, in_w, inw_bf, n4i);

  // graph build
  fill_deg<<<(N + 255) / 256, 256, 0, stream>>>(deg, N);
  count_deg<<<1024, 256, 0, stream>>>(e0, e1, deg, E);
  block_sum<<<NB, 1024, 0, stream>>>(deg, bsum, N);
  scan_final<<<NB, 1024, 0, stream>>>(deg, bsum, row_ptr, cursor, N, NB);
  int span = (N + SC_BUCKETS - 1) / SC_BUCKETS;
  int bpb = 512;
  scatter_edges_b<<<SC_BUCKETS * bpb, 256, 0, stream>>>(
      e0, e1, dist_vec, deg, cursor, ecw, E, N, span, bpb);

  // GCN layers (bf16 storage, MFMA dense)
  const unsigned short* cur_in = emb_bf;
  for (int i = 0; i < GCN_NUM; ++i) {
    spmm_bf<<<(N + 3) / 4, 256, 0, stream>>>(row_ptr, ecw, cur_in, agg_bf, N);
    dense_mfma<<<Npad / 128, 256, 0, stream>>>(
        agg_bf, W_bf + (size_t)i * D * D, gcn_b + (size_t)i * D, enc_bf, N);
    cur_in = enc_bf;
  }

  // gathers + attention
  gather_all<<<BL + B, 64, 0, stream>>>(enc_bf, x_idx, poi_idx, geo_bf,
                                        out + (size_t)B * D, BL, B);
  dim3 qgrid(BL / 128, 3);
  qkv_mfma<<<qgrid, 256, 0, stream>>>(geo_bf, inw_bf, in_b, qkv, BL);
  attn_kernel<<<B * HEADS, 128, 0, stream>>>(qkv, obuf);
  out_mean_kernel<<<B, 128, 0, stream>>>(obuf, out_w, out_b, out, L);
}

// Round 7
// 364.365 us; speedup vs baseline: 2.5143x; 1.0157x over previous
//
#include <hip/hip_runtime.h>
#include <math.h>

#define D 128
#define GCN_NUM 3
#define HEADS 8
#define HD 16
#define L_SEQ 100
#define LEAKY 0.01f
#define SC_BUCKETS 8

typedef __attribute__((ext_vector_type(8))) short short8v;
typedef __attribute__((ext_vector_type(4))) float f32x4;

__device__ __forceinline__ unsigned f2bf(float x) {
  unsigned u = __float_as_uint(x);
  return (u + 0x7FFFu + ((u >> 16) & 1u)) >> 16;
}
__device__ __forceinline__ float bflo2f(unsigned u) { return __uint_as_float(u << 16); }
__device__ __forceinline__ float bfhi2f(unsigned u) { return __uint_as_float(u & 0xFFFF0000u); }

// ---------------- prep: fused f32->bf16 converts (3 segments) + deg init ----------------

__global__ void prep(const float* __restrict__ s0, unsigned short* __restrict__ d0, int n0,
                     const float* __restrict__ s1, unsigned short* __restrict__ d1, int n1,
                     const float* __restrict__ s2, unsigned short* __restrict__ d2, int n2,
                     int* __restrict__ deg, int N) {
  int i = blockIdx.x * blockDim.x + threadIdx.x;
  int n4tot = n0 + n1 + n2;
  if (i < n4tot) {
    const float* s; unsigned short* d; int j;
    if (i < n0)           { s = s0; d = d0; j = i; }
    else if (i < n0 + n1) { s = s1; d = d1; j = i - n0; }
    else                  { s = s2; d = d2; j = i - n0 - n1; }
    float4 v = reinterpret_cast<const float4*>(s)[j];
    uint2 o;
    o.x = f2bf(v.x) | (f2bf(v.y) << 16);
    o.y = f2bf(v.z) | (f2bf(v.w) << 16);
    reinterpret_cast<uint2*>(d)[j] = o;
  } else if (i - n4tot < N) {
    deg[i - n4tot] = 1;  // self-loop
  }
}

// ---------------- graph build ----------------

__global__ void count_deg(const int* __restrict__ e0, const int* __restrict__ e1,
                          int* __restrict__ deg, int E) {
  int stride = gridDim.x * blockDim.x;
  for (int i = blockIdx.x * blockDim.x + threadIdx.x; i < E; i += stride) {
    atomicAdd(&deg[e0[i]], 1);
    atomicAdd(&deg[e1[i]], 1);
  }
}

// ---- parallel exclusive scan over deg (2 kernels; NB <= 64) ----

__global__ __launch_bounds__(1024) void block_sum(const int* __restrict__ deg,
                                                  int* __restrict__ bsum, int n) {
  __shared__ int ws[16];
  int tid = threadIdx.x, lane = tid & 63, wid = tid >> 6;
  int i = blockIdx.x * 1024 + tid;
  int v = (i < n) ? deg[i] : 0;
#pragma unroll
  for (int off = 32; off; off >>= 1) v += __shfl_xor(v, off);
  if (lane == 0) ws[wid] = v;
  __syncthreads();
  if (tid == 0) {
    int s = 0;
#pragma unroll
    for (int k = 0; k < 16; ++k) s += ws[k];
    bsum[blockIdx.x] = s;
  }
}

__global__ __launch_bounds__(1024) void scan_final(
    const int* __restrict__ deg, const int* __restrict__ bsum,
    int* __restrict__ row_ptr, int* __restrict__ cursor, int n, int nb) {
  __shared__ int ws[16];
  __shared__ int prefix_s;
  int tid = threadIdx.x, lane = tid & 63, wid = tid >> 6;
  int i = blockIdx.x * 1024 + tid;
  int v = (i < n) ? deg[i] : 0;
  int x = v;
#pragma unroll
  for (int off = 1; off < 64; off <<= 1) {
    int y = __shfl_up(x, off);
    if (lane >= off) x += y;
  }
  if (lane == 63) ws[wid] = x;
  __syncthreads();
  if (wid == 0) {
    int pv = (lane < blockIdx.x) ? bsum[lane] : 0;
#pragma unroll
    for (int off = 32; off; off >>= 1) pv += __shfl_xor(pv, off);
    if (lane == 0) prefix_s = pv;
    int s = (lane < 16) ? ws[lane] : 0;
#pragma unroll
    for (int off = 1; off < 16; off <<= 1) {
      int y = __shfl_up(s, off);
      if (lane >= off) s += y;
    }
    if (lane < 16) ws[lane] = s;
  }
  __syncthreads();
  int woff = wid ? ws[wid - 1] : 0;
  int prefix = prefix_s;
  if (i < n) {
    int pval = prefix + woff + (x - v);
    row_ptr[i] = pval;
    cursor[i] = pval;
  }
  if (blockIdx.x == nb - 1 && tid == 0) row_ptr[n] = prefix + ws[15];
}

// XCD-local bucketed scatter: bucket = bid & 7 -> all writers of a bucket on one XCD
// (round-robin bid->XCD); bucket's ~850KB ecw slice collects FULL lines in that L2.
__global__ __launch_bounds__(256) void scatter_edges_x(
    const int* __restrict__ e0, const int* __restrict__ e1,
    const float* __restrict__ dv, const int* __restrict__ deg,
    int* __restrict__ cursor, uint2* __restrict__ ecw,
    int E, int N, int span, int bpb) {
  int bucket = blockIdx.x & (SC_BUCKETS - 1);
  int bx = blockIdx.x >> 3;
  int rlo = bucket * span;
  int rhi = min(rlo + span, N);
  int total = 2 * E + N;
  int stride = bpb * 256;
  for (int i = bx * 256 + threadIdx.x; i < total; i += stride) {
    int r, c; bool self = false;
    if (i < E)          { r = e0[i];     c = e1[i]; }
    else if (i < 2 * E) { r = e1[i - E]; c = e0[i - E]; }
    else                { r = i - 2 * E; c = r; self = true; }
    if (r < rlo || r >= rhi) continue;
    float d = self ? 0.f : dv[(i < E) ? i : i - E];
    float w = expf(-d * d) * (1.0f / sqrtf((float)deg[r])) * (1.0f / sqrtf((float)deg[c]));
    int pos = atomicAdd(&cursor[r], 1);
    ecw[pos] = make_uint2((unsigned)c, __float_as_uint(w));
  }
}

// ---------------- GCN ----------------

// SpMM: one row per wave, 4 edge-groups of 16 lanes, 2-deep pipeline per group.
__global__ __launch_bounds__(256) void spmm_bf(
    const int* __restrict__ row_ptr, const uint2* __restrict__ ecw,
    const unsigned short* __restrict__ enc, unsigned short* __restrict__ agg, int n) {
  int r = blockIdx.x * 4 + (threadIdx.x >> 6);
  if (r >= n) return;
  int lane = threadIdx.x & 63;
  int g = lane >> 4, t = lane & 15;
  int s = row_ptr[r], e = row_ptr[r + 1];
  float a0 = 0.f, a1 = 0.f, a2 = 0.f, a3 = 0.f, a4 = 0.f, a5 = 0.f, a6 = 0.f, a7 = 0.f;
  int i = s + g;
  uint2 cwA = make_uint2(0u, 0u), cwB = make_uint2(0u, 0u);
  if (i < e) cwA = ecw[i];
  if (i + 4 < e) cwB = ecw[i + 4];
  while (i + 4 < e) {
    uint2 cwC = cwA, cwD = cwB;
    if (i + 8 < e)  cwC = ecw[i + 8];
    if (i + 12 < e) cwD = ecw[i + 12];
    float wA = __uint_as_float(cwA.y), wB = __uint_as_float(cwB.y);
    uint4 uA = *reinterpret_cast<const uint4*>(enc + (size_t)cwA.x * D + t * 8);
    uint4 uB = *reinterpret_cast<const uint4*>(enc + (size_t)cwB.x * D + t * 8);
    a0 = fmaf(wA, bflo2f(uA.x), a0); a1 = fmaf(wA, bfhi2f(uA.x), a1);
    a2 = fmaf(wA, bflo2f(uA.y), a2); a3 = fmaf(wA, bfhi2f(uA.y), a3);
    a4 = fmaf(wA, bflo2f(uA.z), a4); a5 = fmaf(wA, bfhi2f(uA.z), a5);
    a6 = fmaf(wA, bflo2f(uA.w), a6); a7 = fmaf(wA, bfhi2f(uA.w), a7);
    a0 = fmaf(wB, bflo2f(uB.x), a0); a1 = fmaf(wB, bfhi2f(uB.x), a1);
    a2 = fmaf(wB, bflo2f(uB.y), a2); a3 = fmaf(wB, bfhi2f(uB.y), a3);
    a4 = fmaf(wB, bflo2f(uB.z), a4); a5 = fmaf(wB, bfhi2f(uB.z), a5);
    a6 = fmaf(wB, bflo2f(uB.w), a6); a7 = fmaf(wB, bfhi2f(uB.w), a7);
    cwA = cwC; cwB = cwD;
    i += 8;
  }
  if (i < e) {
    float wA = __uint_as_float(cwA.y);
    uint4 uA = *reinterpret_cast<const uint4*>(enc + (size_t)cwA.x * D + t * 8);
    a0 = fmaf(wA, bflo2f(uA.x), a0); a1 = fmaf(wA, bfhi2f(uA.x), a1);
    a2 = fmaf(wA, bflo2f(uA.y), a2); a3 = fmaf(wA, bfhi2f(uA.y), a3);
    a4 = fmaf(wA, bflo2f(uA.z), a4); a5 = fmaf(wA, bfhi2f(uA.z), a5);
    a6 = fmaf(wA, bflo2f(uA.w), a6); a7 = fmaf(wA, bfhi2f(uA.w), a7);
  }
  a0 += __shfl_xor(a0, 16); a0 += __shfl_xor(a0, 32);
  a1 += __shfl_xor(a1, 16); a1 += __shfl_xor(a1, 32);
  a2 += __shfl_xor(a2, 16); a2 += __shfl_xor(a2, 32);
  a3 += __shfl_xor(a3, 16); a3 += __shfl_xor(a3, 32);
  a4 += __shfl_xor(a4, 16); a4 += __shfl_xor(a4, 32);
  a5 += __shfl_xor(a5, 16); a5 += __shfl_xor(a5, 32);
  a6 += __shfl_xor(a6, 16); a6 += __shfl_xor(a6, 32);
  a7 += __shfl_xor(a7, 16); a7 += __shfl_xor(a7, 32);
  if (g == 0) {
    uint4 o;
    o.x = f2bf(a0) | (f2bf(a1) << 16);
    o.y = f2bf(a2) | (f2bf(a3) << 16);
    o.z = f2bf(a4) | (f2bf(a5) << 16);
    o.w = f2bf(a6) | (f2bf(a7) << 16);
    *reinterpret_cast<uint4*>(agg + (size_t)r * D + t * 8) = o;
  }
}

// enc = normalize(leaky_relu(A @ W^T + b)) via MFMA bf16.
__global__ __launch_bounds__(256) void dense_mfma(
    const unsigned short* __restrict__ A, const unsigned short* __restrict__ Wb,
    const float* __restrict__ bias, unsigned short* __restrict__ enc, int n) {
  __shared__ unsigned short Wl[128 * 136];
  int tid = threadIdx.x;
  {
    int cg = (tid & 15) * 8;
    int r0 = tid >> 4;
#pragma unroll
    for (int i = 0; i < 8; ++i) {
      int row = r0 + i * 16;
      *reinterpret_cast<short8v*>(&Wl[row * 136 + cg]) =
          *reinterpret_cast<const short8v*>(Wb + row * D + cg);
    }
  }
  __syncthreads();
  int w = tid >> 6, lane = tid & 63;
  int lr = lane & 15, lg = lane >> 4;
#pragma unroll
  for (int rt = 0; rt < 2; ++rt) {
    int rbase = blockIdx.x * 128 + rt * 64 + w * 16;
    f32x4 acc[8];
#pragma unroll
    for (int j = 0; j < 8; ++j) acc[j] = f32x4{0.f, 0.f, 0.f, 0.f};
    const unsigned short* arow = A + (size_t)(rbase + lr) * D + lg * 8;
#pragma unroll
    for (int ks = 0; ks < 4; ++ks) {
      short8v a = *reinterpret_cast<const short8v*>(arow + ks * 32);
#pragma unroll
      for (int jt = 0; jt < 8; ++jt) {
        short8v b = *reinterpret_cast<const short8v*>(&Wl[(jt * 16 + lr) * 136 + ks * 32 + lg * 8]);
        acc[jt] = __builtin_amdgcn_mfma_f32_16x16x32_bf16(a, b, acc[jt], 0, 0, 0);
      }
    }
    float vals[8][4];
    float ss[4] = {0.f, 0.f, 0.f, 0.f};
#pragma unroll
    for (int jt = 0; jt < 8; ++jt) {
      float bj = bias[jt * 16 + lr];
#pragma unroll
      for (int i = 0; i < 4; ++i) {
        float t = acc[jt][i] + bj;
        t = (t > 0.f) ? t : LEAKY * t;
        vals[jt][i] = t;
        ss[i] += t * t;
      }
    }
#pragma unroll
    for (int i = 0; i < 4; ++i) {
      float s = ss[i];
      s += __shfl_xor(s, 1); s += __shfl_xor(s, 2);
      s += __shfl_xor(s, 4); s += __shfl_xor(s, 8);
      ss[i] = 1.0f / fmaxf(sqrtf(s), 1e-12f);
    }
#pragma unroll
    for (int i = 0; i < 4; ++i) {
      int row = rbase + lg * 4 + i;
      if (row < n) {
#pragma unroll
        for (int jt = 0; jt < 8; ++jt)
          enc[(size_t)row * D + jt * 16 + lr] = (unsigned short)f2bf(vals[jt][i] * ss[i]);
      }
    }
  }
}

// ---------------- gather + attention ----------------

// tar rows only (geo gather is fused into qkv_mfma)
__global__ void gather_tar(const unsigned short* __restrict__ src,
                           const int* __restrict__ poi_idx, float* __restrict__ tar, int B) {
  int j = blockIdx.x;
  if (j < B) {
    int t = threadIdx.x;  // 64 threads
    unsigned u = reinterpret_cast<const unsigned*>(src + (size_t)poi_idx[j] * D)[t];
    reinterpret_cast<float2*>(tar + (size_t)j * D)[t] = make_float2(bflo2f(u), bfhi2f(u));
  }
}

// qkv via MFMA with fused x_idx row gather: A row = enc[x_idx[row]].
__global__ __launch_bounds__(256) void qkv_mfma(
    const unsigned short* __restrict__ enc, const int* __restrict__ x_idx,
    const unsigned short* __restrict__ Wb, const float* __restrict__ bias,
    float* __restrict__ qkv, int M) {
  __shared__ unsigned short Wl[128 * 136];
  int tid = threadIdx.x;
  const unsigned short* Wslab = Wb + (size_t)blockIdx.y * 128 * D;
  {
    int cg = (tid & 15) * 8;
    int r0 = tid >> 4;
#pragma unroll
    for (int i = 0; i < 8; ++i) {
      int row = r0 + i * 16;
      *reinterpret_cast<short8v*>(&Wl[row * 136 + cg]) =
          *reinterpret_cast<const short8v*>(Wslab + row * D + cg);
    }
  }
  __syncthreads();
  int w = tid >> 6, lane = tid & 63;
  int lr = lane & 15, lg = lane >> 4;
  int colbase = blockIdx.y * 128;
#pragma unroll
  for (int rt = 0; rt < 2; ++rt) {
    int rbase = blockIdx.x * 128 + rt * 64 + w * 16;
    f32x4 acc[8];
#pragma unroll
    for (int j = 0; j < 8; ++j) acc[j] = f32x4{0.f, 0.f, 0.f, 0.f};
    const unsigned short* arow = enc + (size_t)x_idx[rbase + lr] * D + lg * 8;
#pragma unroll
    for (int ks = 0; ks < 4; ++ks) {
      short8v a = *reinterpret_cast<const short8v*>(arow + ks * 32);
#pragma unroll
      for (int jt = 0; jt < 8; ++jt) {
        short8v b = *reinterpret_cast<const short8v*>(&Wl[(jt * 16 + lr) * 136 + ks * 32 + lg * 8]);
        acc[jt] = __builtin_amdgcn_mfma_f32_16x16x32_bf16(a, b, acc[jt], 0, 0, 0);
      }
    }
#pragma unroll
    for (int jt = 0; jt < 8; ++jt) {
      int j = colbase + jt * 16 + lr;
      float bj = bias[j];
#pragma unroll
      for (int i = 0; i < 4; ++i) {
        int row = rbase + lg * 4 + i;
        if (row < M) qkv[(size_t)row * 384 + j] = acc[jt][i] + bj;
      }
    }
  }
}

__global__ __launch_bounds__(128) void attn_kernel(
    const float* __restrict__ qkv, float* __restrict__ o) {
  __shared__ float k_s[L_SEQ][HD];
  __shared__ float v_s[L_SEQ][HD];
  __shared__ float sc[L_SEQ][L_SEQ + 1];
  int b = blockIdx.x / HEADS;
  int h = blockIdx.x % HEADS;
  int tid = threadIdx.x;
  const size_t rowbase = (size_t)b * L_SEQ;
  for (int idx = tid; idx < L_SEQ * HD; idx += 128) {
    int l = idx >> 4, d2 = idx & 15;
    const float* base = qkv + (rowbase + l) * 384 + h * HD + d2;
    k_s[l][d2] = base[128];
    v_s[l][d2] = base[256];
  }
  __syncthreads();
  if (tid < L_SEQ) {
    float q[HD];
    const float* qp = qkv + (rowbase + tid) * 384 + h * HD;
#pragma unroll
    for (int d2 = 0; d2 < HD; ++d2) q[d2] = qp[d2];
    float m = -1e30f;
    for (int j = 0; j < L_SEQ; ++j) {
      float s = 0.f;
#pragma unroll
      for (int d2 = 0; d2 < HD; ++d2) s += q[d2] * k_s[j][d2];
      s *= 0.25f;
      sc[tid][j] = s;
      m = fmaxf(m, s);
    }
    float sum = 0.f;
    for (int j = 0; j < L_SEQ; ++j) {
      float e = expf(sc[tid][j] - m);
      sc[tid][j] = e;
      sum += e;
    }
    float inv = 1.f / sum;
    float oacc[HD];
#pragma unroll
    for (int d2 = 0; d2 < HD; ++d2) oacc[d2] = 0.f;
    for (int j = 0; j < L_SEQ; ++j) {
      float p = sc[tid][j];
#pragma unroll
      for (int d2 = 0; d2 < HD; ++d2) oacc[d2] += p * v_s[j][d2];
    }
    float* op = o + (rowbase + tid) * D + h * HD;
#pragma unroll
    for (int d2 = 0; d2 < HD; ++d2) op[d2] = oacc[d2] * inv;
  }
}

__global__ __launch_bounds__(128) void out_mean_kernel(
    const float* __restrict__ o, const float* __restrict__ Wo,
    const float* __restrict__ bo, float* __restrict__ out, int L) {
  __shared__ float m_s[D];
  int b = blockIdx.x, tid = threadIdx.x;
  float s = 0.f;
  for (int l = 0; l < L; ++l) s += o[((size_t)b * L + l) * D + tid];
  m_s[tid] = s / (float)L;
  __syncthreads();
  const float4* w4 = reinterpret_cast<const float4*>(Wo + (size_t)tid * D);
  float acc = 0.f;
  for (int k4 = 0; k4 < D / 4; ++k4) {
    float4 w = w4[k4];
    int k = k4 * 4;
    acc += m_s[k] * w.x + m_s[k + 1] * w.y + m_s[k + 2] * w.z + m_s[k + 3] * w.w;
  }
  out[(size_t)b * D + tid] = acc + bo[tid];
}

// ---------------- launch ----------------

extern "C" void kernel_launch(void* const* d_in, const int* in_sizes, int n_in,
                              void* d_out, int out_size, void* d_ws, size_t ws_size,
                              hipStream_t stream) {
  const float* embeds   = (const float*)d_in[0];
  const float* gcn_W    = (const float*)d_in[1];
  const float* gcn_b    = (const float*)d_in[2];
  const float* in_w     = (const float*)d_in[3];
  const float* in_b     = (const float*)d_in[4];
  const float* out_w    = (const float*)d_in[5];
  const float* out_b    = (const float*)d_in[6];
  const float* dist_vec = (const float*)d_in[7];
  const int*   edges    = (const int*)d_in[8];
  const int*   x_idx    = (const int*)d_in[9];
  const int*   poi_idx  = (const int*)d_in[10];
  float* out = (float*)d_out;

  int N  = in_sizes[0] / D;   // 50000
  int E  = in_sizes[7];       // 400000
  int BL = in_sizes[9];       // 6400
  int B  = in_sizes[10];      // 64
  int L  = BL / B;            // 100
  const int* e0 = edges;
  const int* e1 = edges + E;
  size_t total_edges = (size_t)2 * E + N;          // 850000
  int Npad = ((N + 127) / 128) * 128;              // 50048
  int NB   = (N + 1023) / 1024;                    // 49 (<= 64)

  char* p = (char*)d_ws;
  auto alloc = [&](size_t bytes) { char* q = p; p += (bytes + 255) & ~(size_t)255; return q; };
  int*   deg     = (int*)alloc((size_t)N * 4);
  int*   row_ptr = (int*)alloc((size_t)(N + 1) * 4);
  int*   cursor  = (int*)alloc((size_t)N * 4);
  int*   bsum    = (int*)alloc((size_t)NB * 4);
  uint2* ecw     = (uint2*)alloc(total_edges * 8);
  unsigned short* emb_bf = (unsigned short*)alloc((size_t)Npad * D * 2);
  unsigned short* W_bf   = (unsigned short*)alloc((size_t)GCN_NUM * D * D * 2);
  unsigned short* inw_bf = (unsigned short*)alloc((size_t)3 * D * D * 2);
  unsigned short* agg_bf = (unsigned short*)alloc((size_t)Npad * D * 2);
  unsigned short* enc_bf = (unsigned short*)alloc((size_t)Npad * D * 2);
  float* qkv  = (float*)alloc((size_t)BL * 384 * 4);
  float* obuf = (float*)alloc((size_t)BL * D * 4);

  // fused converts + deg init
  int n4e = N * D / 4, n4w = GCN_NUM * D * D / 4, n4i = 3 * D * D / 4;
  int prep_tot = n4e + n4w + n4i + N;
  prep<<<(prep_tot + 255) / 256, 256, 0, stream>>>(
      embeds, emb_bf, n4e, gcn_W, W_bf, n4w, in_w, inw_bf, n4i, deg, N);

  // graph build
  count_deg<<<1024, 256, 0, stream>>>(e0, e1, deg, E);
  block_sum<<<NB, 1024, 0, stream>>>(deg, bsum, N);
  scan_final<<<NB, 1024, 0, stream>>>(deg, bsum, row_ptr, cursor, N, NB);
  int span = (N + SC_BUCKETS - 1) / SC_BUCKETS;
  int bpb = 512;
  scatter_edges_x<<<SC_BUCKETS * bpb, 256, 0, stream>>>(
      e0, e1, dist_vec, deg, cursor, ecw, E, N, span, bpb);

  // GCN layers (bf16 storage, MFMA dense)
  const unsigned short* cur_in = emb_bf;
  for (int i = 0; i < GCN_NUM; ++i) {
    spmm_bf<<<(N + 3) / 4, 256, 0, stream>>>(row_ptr, ecw, cur_in, agg_bf, N);
    dense_mfma<<<Npad / 128, 256, 0, stream>>>(
        agg_bf, W_bf + (size_t)i * D * D, gcn_b + (size_t)i * D, enc_bf, N);
    cur_in = enc_bf;
  }

  // gathers + attention
  gather_tar<<<B, 64, 0, stream>>>(enc_bf, poi_idx, out + (size_t)B * D, B);
  dim3 qgrid(BL / 128, 3);
  qkv_mfma<<<qgrid, 256, 0, stream>>>(enc_bf, x_idx, inw_bf, in_b, qkv, BL);
  attn_kernel<<<B * HEADS, 128, 0, stream>>>(qkv, obuf);
  out_mean_kernel<<<B, 128, 0, stream>>>(obuf, out_w, out_b, out, L);
}